// Round 12
// baseline (889.475 us; speedup 1.0000x reference)
//
#include <hip/hip_runtime.h>
#include <math.h>

#define LEAKY(x) ((x) > 0.f ? (x) : 0.01f * (x))
static constexpr float BN_SCALE = 0.9999950000374997f;

typedef unsigned short ushort_t;
typedef float f32x4 __attribute__((ext_vector_type(4)));
typedef short bf16x8 __attribute__((ext_vector_type(8)));

__device__ __forceinline__ ushort_t f2bfu(float f) {
  union { float f; unsigned u; } v; v.f = f;
  unsigned r = v.u + 0x7fffu + ((v.u >> 16) & 1u);
  return (ushort_t)(r >> 16);
}
__device__ __forceinline__ float bfu2f(ushort_t u) {
  union { unsigned u; float f; } v; v.u = ((unsigned)u) << 16;
  return v.f;
}

// ---- async global->LDS, 16B per lane (dest = wave-uniform base + lane*16) --
__device__ __forceinline__ void gload16(const ushort_t* g, ushort_t* lds) {
  __builtin_amdgcn_global_load_lds(
      (const __attribute__((address_space(1))) void*)g,
      (__attribute__((address_space(3))) void*)lds, 16, 0, 0);
}

__global__ void fill_out(float* out, int n) {
  int i = blockIdx.x * 256 + threadIdx.x;
  if (i < n) out[i] = 0.25f;
}

// ---- one-shot fp32 -> bf16 conversion, flat-indexed over all tensors ------
struct CvtArgs {
  const float* src[20];
  ushort_t* dst[20];
  int cum[21];
};
__global__ void to_bf16_flat(CvtArgs a) {
  int total = a.cum[20];
  for (int i = blockIdx.x * 256 + threadIdx.x; i < total; i += gridDim.x * 256) {
    int s = 0;
    while (i >= a.cum[s + 1]) ++s;
    int off = i - a.cum[s];
    a.dst[s][off] = f2bfu(a.src[s][off]);
  }
}

// ---- pack 6 bias pairs [128|128] -> fp32 [6][256] -------------------------
struct BiasPk { const float* a[12]; float* out; };
__global__ void bias_pack(BiasPk p) {
  int b = blockIdx.x, t = threadIdx.x;
  p.out[b * 256 + t] = (t < 128) ? p.a[2 * b][t] : p.a[2 * b + 1][t - 128];
}

// ---- generic row pad: fp32 [O][Kin] -> bf16 [O][Kpad] with zero fill ------
__global__ void pad_rows_bf16(const float* __restrict__ w, ushort_t* __restrict__ wp,
                              int O, int Kin, int Kpad) {
  int idx = blockIdx.x * 256 + threadIdx.x;
  if (idx >= O * Kpad) return;
  int o = idx / Kpad, k = idx - o * Kpad;
  wp[idx] = (k < Kin) ? f2bfu(w[(size_t)o * Kin + k]) : (ushort_t)0;
}

// ---- conv2 weight relayout: w2[50][20][25] -> w2p[64][tap*24+ic] bf16 -----
__global__ void w2_relayout(const float* __restrict__ w2, ushort_t* __restrict__ w2p) {
  int idx = blockIdx.x * 256 + threadIdx.x;  // 64*640
  if (idx >= 64 * 640) return;
  int oc = idx / 640, k = idx - oc * 640;
  int tap = k / 24, ic = k - tap * 24;
  float v = 0.f;
  if (oc < 50 && tap < 25 && ic < 20)
    v = w2[(size_t)(oc * 20 + ic) * 25 + tap];
  w2p[idx] = f2bfu(v);
}

// ---- XCD-aware bijective block swizzle (grid size divisible by 8) ---------
#define XCD_SWZ(TILE)                                                          \
  int id_ = blockIdx.y * gridDim.x + blockIdx.x;                               \
  int nwg_ = gridDim.x * gridDim.y;                                            \
  int sw_ = (id_ & 7) * (nwg_ >> 3) + (id_ >> 3);                              \
  int bm = (sw_ / gridDim.x) * (TILE), bn = (sw_ % gridDim.x) * (TILE);

// ============================================================================
// conv1 + leaky + 2x2 maxpool (phase A standalone). 2 images/block.
// Writes h1T [img][pos][c24] bf16 to global via coalesced uint4 dump.
// Standalone: no MFMA state -> low VGPR -> ~2x occupancy vs the fused kernel.
// ============================================================================
__launch_bounds__(256)
__global__ void conv1_pool(const float* __restrict__ imgB, const float* __restrict__ imgK,
                           const float* __restrict__ w1, const float* __restrict__ b1,
                           ushort_t* __restrict__ h1g) {
  __shared__ __align__(16) char smem[23072];
  ushort_t* h1T = (ushort_t*)smem;               // [0,13824)
  float* simg = (float*)(smem + 13824);          // 7168
  float* sw1  = (float*)(smem + 20992);          // 2000
  float* b1s  = (float*)(smem + 22992);          // 80

  int tid = threadIdx.x;
  int bx = blockIdx.x;
  const float* imgb = (bx < 1024) ? imgB + (size_t)bx * 2 * 784
                                  : imgK + (size_t)(bx - 1024) * 2 * 784;

  for (int i = tid; i < 1568; i += 256) {
    int im = (i >= 784) ? 1 : 0;
    int r = i - im * 784;
    int row = r / 28, col = r - row * 28;
    simg[im * 896 + row * 32 + col] = imgb[i];
  }
  for (int i = tid; i < 500; i += 256) sw1[i] = w1[i];
  if (tid < 20) b1s[tid] = b1[tid];
  for (int i = tid; i < 288; i += 256) {
    uint2 z; z.x = 0; z.y = 0;
    *(uint2*)&h1T[i * 24 + 20] = z;
  }
  __syncthreads();

  // cg in low 2 bits of the item index (5 channels per item)
  for (int o = tid; o < 1152; o += 256) {
    int im = (o >= 576) ? 1 : 0;
    int rem = o - im * 576;
    int cg = rem & 3;
    int pos = rem >> 2;
    int py = pos / 12, px = pos - py * 12;
    int y0 = py * 2, x0 = px * 2;
    float p[6][6];
    #pragma unroll
    for (int yy = 0; yy < 6; ++yy) {
      const float* rb = &simg[im * 896 + (y0 + yy) * 32 + x0];
      #pragma unroll
      for (int xx = 0; xx < 6; ++xx)
        p[yy][xx] = rb[xx];
    }
    #pragma unroll
    for (int cc = 0; cc < 5; ++cc) {
      int c = cg * 5 + cc;
      const float* wc = &sw1[c * 25];
      float bb = b1s[c];
      float t0 = bb, t1 = bb, t2 = bb, t3 = bb;
      #pragma unroll
      for (int ky = 0; ky < 5; ++ky)
        #pragma unroll
        for (int kx = 0; kx < 5; ++kx) {
          float wv = wc[ky * 5 + kx];
          t0 += p[ky][kx] * wv;
          t1 += p[ky][kx + 1] * wv;
          t2 += p[ky + 1][kx] * wv;
          t3 += p[ky + 1][kx + 1] * wv;
        }
      float mx = fmaxf(fmaxf(t0, t1), fmaxf(t2, t3));
      h1T[(im * 144 + pos) * 24 + c] = f2bfu(LEAKY(mx));
    }
  }
  __syncthreads();
  // coalesced dump (6912 ushorts = 864 uint4)
  const uint4* src4 = (const uint4*)h1T;
  uint4* dst4 = (uint4*)(h1g + (size_t)bx * 6912);
  for (int i = tid; i < 864; i += 256) dst4[i] = src4[i];
}

// ============================================================================
// conv2 MFMA (phase B standalone). 2 images/block. Stages h1T from global via
// 4 uniform gload16 rounds (layout byte-identical to conv1's dump); gather +
// MFMA + pool epilogue unchanged. Output stride 832 (zero-padded 800->832).
// ============================================================================
__launch_bounds__(256)
__global__ void conv2_mfma(const ushort_t* __restrict__ h1g,
                           const ushort_t* __restrict__ w2p, const float* __restrict__ b2,
                           ushort_t* __restrict__ out832) {
  __shared__ __align__(16) char smem[34816];
  ushort_t* h1T = (ushort_t*)smem;               // [0,16384) staged (13824 used)
  ushort_t* Bs  = (ushort_t*)(smem + 16384);     // 9216
  float* Cf   = (float*)smem;                    // epilogue (34816)

  int tid = threadIdx.x;
  int bx = blockIdx.x;

  int sB_r = tid >> 2;
  int sB_j0 = (tid & 3) * 2;
  bf16x8 wreg[2];
  #pragma unroll
  for (int i = 0; i < 2; ++i)
    wreg[i] = *(const bf16x8*)&w2p[(size_t)sB_r * 640 + (sB_j0 + i) * 8];

  const ushort_t* gsrc = h1g + (size_t)bx * 6912;
  #pragma unroll
  for (int r = 0; r < 4; ++r)
    gload16(gsrc + (r * 256 + tid) * 8, &h1T[(r * 256 + tid) * 8]);

  int wave = tid >> 6, lane = tid & 63;
  int wm = (wave >> 1) * 64, wn = (wave & 1) * 32;
  int mrow = lane & 15, kq = lane >> 4;

  int imv[4], oyv[4], oxv[4];
  #pragma unroll
  for (int mt = 0; mt < 4; ++mt) {
    int r = wm + mt * 16 + mrow;
    imv[mt] = r >> 6;
    int op = r & 63;
    oyv[mt] = op >> 3;
    oxv[mt] = op & 7;
  }

  f32x4 acc[4][2];
  #pragma unroll
  for (int i = 0; i < 4; ++i)
    #pragma unroll
    for (int j = 0; j < 2; ++j)
      #pragma unroll
      for (int r = 0; r < 4; ++r) acc[i][j][r] = 0.f;

  for (int kb = 0; kb < 10; ++kb) {
    __syncthreads();   // kb=0: drains staging gloads (barrier waits vmcnt)
    #pragma unroll
    for (int i = 0; i < 2; ++i)
      *(bf16x8*)&Bs[sB_r * 72 + (sB_j0 + i) * 8] = wreg[i];
    if (kb + 1 < 10) {
      #pragma unroll
      for (int i = 0; i < 2; ++i)
        wreg[i] = *(const bf16x8*)&w2p[(size_t)sB_r * 640 + (kb + 1) * 64 + (sB_j0 + i) * 8];
    }
    __syncthreads();
    #pragma unroll
    for (int ks = 0; ks < 2; ++ks) {
      int g = kb * 8 + ks * 4 + kq;
      int tap = g / 3;
      int part = g - tap * 3;
      int tc = tap < 25 ? tap : 24;
      int ky = tc / 5, kx = tc - ky * 5;
      bf16x8 af[4], bf[2];
      #pragma unroll
      for (int mt = 0; mt < 4; ++mt) {
        int pos = (oyv[mt] + ky) * 12 + oxv[mt] + kx;
        af[mt] = *(const bf16x8*)&h1T[(imv[mt] * 144 + pos) * 24 + part * 8];
      }
      #pragma unroll
      for (int nt = 0; nt < 2; ++nt)
        bf[nt] = *(const bf16x8*)&Bs[(wn + nt * 16 + mrow) * 72 + ks * 32 + kq * 8];
      #pragma unroll
      for (int mt = 0; mt < 4; ++mt)
        #pragma unroll
        for (int nt = 0; nt < 2; ++nt)
          acc[mt][nt] = __builtin_amdgcn_mfma_f32_16x16x32_bf16(af[mt], bf[nt], acc[mt][nt], 0, 0, 0);
    }
  }
  __syncthreads();
  #pragma unroll
  for (int mt = 0; mt < 4; ++mt)
    #pragma unroll
    for (int nt = 0; nt < 2; ++nt) {
      int n0 = wn + nt * 16 + (lane & 15);
      #pragma unroll
      for (int r = 0; r < 4; ++r)
        Cf[(wm + mt * 16 + kq * 4 + r) * 68 + n0] = acc[mt][nt][r];
    }
  __syncthreads();
  for (int o = tid; o < 1664; o += 256) {
    int im = o / 832, oi = o - im * 832;
    ushort_t val = 0;
    if (oi < 800) {
      int oc = oi >> 4, p = oi & 15, py = p >> 2, px = p & 3;
      int r0 = im * 64 + py * 16 + px * 2;
      float bb = b2[oc];
      float t0 = LEAKY(Cf[r0 * 68 + oc] + bb);
      float t1 = LEAKY(Cf[(r0 + 1) * 68 + oc] + bb);
      float t2 = LEAKY(Cf[(r0 + 8) * 68 + oc] + bb);
      float t3 = LEAKY(Cf[(r0 + 9) * 68 + oc] + bb);
      val = f2bfu(fmaxf(fmaxf(t0, t1), fmaxf(t2, t3)));
    }
    out832[(size_t)(bx * 2 + im) * 832 + oi] = val;
  }
}

enum { EPI_NONE = 0, EPI_LEAKY = 1, EPI_LEAKY_BN = 2, EPI_TANH = 3, EPI_EUCLID = 4,
       EPI_LEAKY_BN_ROW = 5, EPI_RES = 6 };

// ---- 128x128 bf16 NT GEMM, BK=64, pipelined gloads, XCD swizzle -----------
template <int EPI>
__launch_bounds__(256)
__global__ void gemm_bf16_nt(const ushort_t* __restrict__ A, const ushort_t* __restrict__ B,
                             const float* __restrict__ bias, float* __restrict__ C32,
                             ushort_t* __restrict__ C16, int M, int N, int Kd,
                             const float* __restrict__ e1, const float* __restrict__ e2) {
  __shared__ __align__(16) ushort_t As[2][8192];
  __shared__ __align__(16) ushort_t Bs[2][8192];
  int tid = threadIdx.x;
  XCD_SWZ(128)
  int wave = tid >> 6, lane = tid & 63;
  int wm = (wave >> 1) * 64, wn = (wave & 1) * 64;
  int mrow = lane & 15, kq = lane >> 4;
  int cc[4];
  const ushort_t* ga[4];
  const ushort_t* gb[4];
  #pragma unroll
  for (int q = 0; q < 4; ++q) {
    int c = (wave * 4 + q) * 64 + lane;
    cc[q] = c;
    int row = (c >> 2) & 127, sl = c >> 9, j = c & 3;
    ga[q] = A + (size_t)(bm + row) * Kd + sl * 32 + j * 8;
    gb[q] = B + (size_t)(bn + row) * Kd + sl * 32 + j * 8;
  }

  f32x4 acc[4][4];
  #pragma unroll
  for (int i = 0; i < 4; ++i)
    #pragma unroll
    for (int j = 0; j < 4; ++j)
      #pragma unroll
      for (int r = 0; r < 4; ++r) acc[i][j][r] = 0.f;

  #pragma unroll
  for (int q = 0; q < 4; ++q) {
    gload16(ga[q], &As[0][cc[q] * 8]);
    gload16(gb[q], &Bs[0][cc[q] * 8]);
  }
  int nt = Kd >> 6;
  for (int t = 0; t < nt; ++t) {
    int cur = t & 1;
    __syncthreads();
    if (t + 1 < nt) {
      int ko = (t + 1) * 64;
      #pragma unroll
      for (int q = 0; q < 4; ++q) {
        gload16(ga[q] + ko, &As[cur ^ 1][cc[q] * 8]);
        gload16(gb[q] + ko, &Bs[cur ^ 1][cc[q] * 8]);
      }
    }
    #pragma unroll
    for (int ks = 0; ks < 2; ++ks) {
      bf16x8 af[4], bf[4];
      #pragma unroll
      for (int mt = 0; mt < 4; ++mt)
        af[mt] = *(const bf16x8*)&As[cur][ks * 4096 + (wm + mt * 16 + mrow) * 32 + kq * 8];
      #pragma unroll
      for (int nt2 = 0; nt2 < 4; ++nt2)
        bf[nt2] = *(const bf16x8*)&Bs[cur][ks * 4096 + (wn + nt2 * 16 + mrow) * 32 + kq * 8];
      #pragma unroll
      for (int mt = 0; mt < 4; ++mt)
        #pragma unroll
        for (int nt2 = 0; nt2 < 4; ++nt2)
          acc[mt][nt2] = __builtin_amdgcn_mfma_f32_16x16x32_bf16(af[mt], bf[nt2], acc[mt][nt2], 0, 0, 0);
    }
  }
  #pragma unroll
  for (int mt = 0; mt < 4; ++mt)
    #pragma unroll
    for (int nt2 = 0; nt2 < 4; ++nt2) {
      int n_g = bn + wn + nt2 * 16 + (lane & 15);
      #pragma unroll
      for (int r = 0; r < 4; ++r) {
        int m_g = bm + wm + mt * 16 + kq * 4 + r;
        float v = acc[mt][nt2][r];
        if (EPI == EPI_EUCLID) {
          v = e1[m_g] + e2[n_g] - 2.f * v;
          v = sqrtf(fmaxf(v, 0.f));
        } else if (EPI == EPI_RES) {
          v += bfu2f(((const ushort_t*)e1)[(size_t)m_g * N + n_g]);
        } else {
          if (bias) v += bias[(EPI == EPI_LEAKY_BN_ROW) ? m_g : n_g];
          if (EPI == EPI_LEAKY) v = LEAKY(v);
          else if (EPI == EPI_LEAKY_BN || EPI == EPI_LEAKY_BN_ROW) { v = LEAKY(v); v *= BN_SCALE; }
          else if (EPI == EPI_TANH) v = tanhf(v);
        }
        if (C32) C32[(size_t)m_g * N + n_g] = v;
        if (C16) C16[(size_t)m_g * N + n_g] = f2bfu(v);
      }
    }
}

// ---- Smat z-GEMM: Smat_z = X12_z[:, :128] @ X12_z[:, 128:]^T, BK=64 -------
__launch_bounds__(256)
__global__ void gemm_smat_z(const ushort_t* __restrict__ X12, ushort_t* __restrict__ Smat) {
  int z = blockIdx.z;
  const ushort_t* A = X12 + (size_t)z * 2048 * 256;
  const ushort_t* B = A + 128;
  ushort_t* C = Smat + (size_t)z * 2048 * 2048;
  __shared__ __align__(16) ushort_t As[2][8192];
  __shared__ __align__(16) ushort_t Bs[2][8192];
  int tid = threadIdx.x;
  XCD_SWZ(128)
  int wave = tid >> 6, lane = tid & 63;
  int wm = (wave >> 1) * 64, wn = (wave & 1) * 64;
  int mrow = lane & 15, kq = lane >> 4;
  int cc[4];
  const ushort_t* ga[4];
  const ushort_t* gb[4];
  #pragma unroll
  for (int q = 0; q < 4; ++q) {
    int c = (wave * 4 + q) * 64 + lane;
    cc[q] = c;
    int row = (c >> 2) & 127, sl = c >> 9, j = c & 3;
    ga[q] = A + (size_t)(bm + row) * 256 + sl * 32 + j * 8;
    gb[q] = B + (size_t)(bn + row) * 256 + sl * 32 + j * 8;
  }

  f32x4 acc[4][4];
  #pragma unroll
  for (int i = 0; i < 4; ++i)
    #pragma unroll
    for (int j = 0; j < 4; ++j)
      #pragma unroll
      for (int r = 0; r < 4; ++r) acc[i][j][r] = 0.f;

  #pragma unroll
  for (int q = 0; q < 4; ++q) {
    gload16(ga[q], &As[0][cc[q] * 8]);
    gload16(gb[q], &Bs[0][cc[q] * 8]);
  }
  for (int t = 0; t < 2; ++t) {
    int cur = t & 1;
    __syncthreads();
    if (t + 1 < 2) {
      int ko = (t + 1) * 64;
      #pragma unroll
      for (int q = 0; q < 4; ++q) {
        gload16(ga[q] + ko, &As[cur ^ 1][cc[q] * 8]);
        gload16(gb[q] + ko, &Bs[cur ^ 1][cc[q] * 8]);
      }
    }
    #pragma unroll
    for (int ks = 0; ks < 2; ++ks) {
      bf16x8 af[4], bf[4];
      #pragma unroll
      for (int mt = 0; mt < 4; ++mt)
        af[mt] = *(const bf16x8*)&As[cur][ks * 4096 + (wm + mt * 16 + mrow) * 32 + kq * 8];
      #pragma unroll
      for (int nt2 = 0; nt2 < 4; ++nt2)
        bf[nt2] = *(const bf16x8*)&Bs[cur][ks * 4096 + (wn + nt2 * 16 + mrow) * 32 + kq * 8];
      #pragma unroll
      for (int mt = 0; mt < 4; ++mt)
        #pragma unroll
        for (int nt2 = 0; nt2 < 4; ++nt2)
          acc[mt][nt2] = __builtin_amdgcn_mfma_f32_16x16x32_bf16(af[mt], bf[nt2], acc[mt][nt2], 0, 0, 0);
    }
  }
  #pragma unroll
  for (int mt = 0; mt < 4; ++mt)
    #pragma unroll
    for (int nt2 = 0; nt2 < 4; ++nt2) {
      int n_g = bn + wn + nt2 * 16 + (lane & 15);
      #pragma unroll
      for (int r = 0; r < 4; ++r) {
        int m_g = bm + wm + mt * 16 + kq * 4 + r;
        C[(size_t)m_g * 2048 + n_g] = f2bfu(acc[mt][nt2][r]);
      }
    }
}

// ---- 64x64 family BK=64 staging macro body (bm/bn set by caller) ----------
#define GEMM64_PRE(Aptr, Bptr, KD)                                             \
  int wave = tid >> 6, lane = tid & 63;                                        \
  int wm = (wave >> 1) * 32, wn = (wave & 1) * 32;                             \
  int mrow = lane & 15, kq = lane >> 4;                                        \
  int c0 = wave * 128 + lane;                                                  \
  int c1 = c0 + 64;                                                            \
  int r0_ = (c0 >> 2) & 63, s0_ = c0 >> 8, j0_ = c0 & 3;                       \
  int r1_ = (c1 >> 2) & 63, s1_ = c1 >> 8, j1_ = c1 & 3;                       \
  const ushort_t* ga0 = Aptr + (size_t)(bm + r0_) * KD + s0_ * 32 + j0_ * 8;   \
  const ushort_t* ga1 = Aptr + (size_t)(bm + r1_) * KD + s1_ * 32 + j1_ * 8;   \
  const ushort_t* gb0 = Bptr + (size_t)(bn + r0_) * KD + s0_ * 32 + j0_ * 8;   \
  const ushort_t* gb1 = Bptr + (size_t)(bn + r1_) * KD + s1_ * 32 + j1_ * 8;

#define GEMM64_LOOP(KD)                                                        \
  gload16(ga0, &As[0][c0 * 8]);                                                \
  gload16(ga1, &As[0][c1 * 8]);                                                \
  gload16(gb0, &Bs[0][c0 * 8]);                                                \
  gload16(gb1, &Bs[0][c1 * 8]);                                                \
  int ntile = (KD) >> 6;                                                       \
  for (int t = 0; t < ntile; ++t) {                                            \
    int cur = t & 1;                                                           \
    __syncthreads();                                                           \
    if (t + 1 < ntile) {                                                       \
      int ko = (t + 1) * 64;                                                   \
      gload16(ga0 + ko, &As[cur ^ 1][c0 * 8]);                                 \
      gload16(ga1 + ko, &As[cur ^ 1][c1 * 8]);                                 \
      gload16(gb0 + ko, &Bs[cur ^ 1][c0 * 8]);                                 \
      gload16(gb1 + ko, &Bs[cur ^ 1][c1 * 8]);                                 \
    }                                                                          \
    _Pragma("unroll")                                                          \
    for (int ks = 0; ks < 2; ++ks) {                                           \
      bf16x8 af[2], bf[2];                                                     \
      _Pragma("unroll")                                                        \
      for (int mt = 0; mt < 2; ++mt)                                           \
        af[mt] = *(const bf16x8*)&As[cur][ks * 2048 + (wm + mt * 16 + mrow) * 32 + kq * 8]; \
      _Pragma("unroll")                                                        \
      for (int nt2 = 0; nt2 < 2; ++nt2)                                        \
        bf[nt2] = *(const bf16x8*)&Bs[cur][ks * 2048 + (wn + nt2 * 16 + mrow) * 32 + kq * 8]; \
      _Pragma("unroll")                                                        \
      for (int mt = 0; mt < 2; ++mt)                                           \
        _Pragma("unroll")                                                      \
        for (int nt2 = 0; nt2 < 2; ++nt2)                                      \
          acc[mt][nt2] = __builtin_amdgcn_mfma_f32_16x16x32_bf16(af[mt], bf[nt2], acc[mt][nt2], 0, 0, 0); \
    }                                                                          \
  }

// ---- 64x64 bf16 NT GEMM, BK=64 --------------------------------------------
template <int EPI>
__launch_bounds__(256)
__global__ void gemm_bf16_nt64(const ushort_t* __restrict__ A, const ushort_t* __restrict__ B,
                               const float* __restrict__ bias, float* __restrict__ C32,
                               ushort_t* __restrict__ C16, int M, int N, int Kd) {
  __shared__ __align__(16) ushort_t As[2][4096];
  __shared__ __align__(16) ushort_t Bs[2][4096];
  int tid = threadIdx.x;
  XCD_SWZ(64)
  GEMM64_PRE(A, B, Kd)
  f32x4 acc[2][2];
  #pragma unroll
  for (int i = 0; i < 2; ++i)
    #pragma unroll
    for (int j = 0; j < 2; ++j)
      #pragma unroll
      for (int r = 0; r < 4; ++r) acc[i][j][r] = 0.f;
  GEMM64_LOOP(Kd)
  #pragma unroll
  for (int mt = 0; mt < 2; ++mt)
    #pragma unroll
    for (int nt2 = 0; nt2 < 2; ++nt2) {
      int n_g = bn + wn + nt2 * 16 + (lane & 15);
      #pragma unroll
      for (int r = 0; r < 4; ++r) {
        int m_g = bm + wm + mt * 16 + kq * 4 + r;
        float v = acc[mt][nt2][r];
        if (bias) v += bias[n_g];
        if (EPI == EPI_LEAKY) v = LEAKY(v);
        else if (EPI == EPI_LEAKY_BN) { v = LEAKY(v); v *= BN_SCALE; }
        else if (EPI == EPI_TANH) v = tanhf(v);
        if (C32) C32[(size_t)m_g * N + n_g] = v;
        if (C16) C16[(size_t)m_g * N + n_g] = f2bfu(v);
      }
    }
}

// ---- 64x64 NT GEMM, dual weight/bias selected by M-half, BK=64 ------------
template <int EPI>
__launch_bounds__(256)
__global__ void gemm_nt64_dual(const ushort_t* __restrict__ A, const ushort_t* __restrict__ B1,
                               const ushort_t* __restrict__ B2, const float* __restrict__ bias1,
                               const float* __restrict__ bias2, ushort_t* __restrict__ C16,
                               int M, int N, int Kd, int Msplit) {
  __shared__ __align__(16) ushort_t As[2][4096];
  __shared__ __align__(16) ushort_t Bs[2][4096];
  int tid = threadIdx.x;
  XCD_SWZ(64)
  const ushort_t* B = (bm < Msplit) ? B1 : B2;
  const float* bias = (bm < Msplit) ? bias1 : bias2;
  GEMM64_PRE(A, B, Kd)
  f32x4 acc[2][2];
  #pragma unroll
  for (int i = 0; i < 2; ++i)
    #pragma unroll
    for (int j = 0; j < 2; ++j)
      #pragma unroll
      for (int r = 0; r < 4; ++r) acc[i][j][r] = 0.f;
  GEMM64_LOOP(Kd)
  #pragma unroll
  for (int mt = 0; mt < 2; ++mt)
    #pragma unroll
    for (int nt2 = 0; nt2 < 2; ++nt2) {
      int n_g = bn + wn + nt2 * 16 + (lane & 15);
      #pragma unroll
      for (int r = 0; r < 4; ++r) {
        int m_g = bm + wm + mt * 16 + kq * 4 + r;
        float v = acc[mt][nt2][r] + bias[n_g];
        if (EPI == EPI_LEAKY) v = LEAKY(v);
        else if (EPI == EPI_LEAKY_BN) { v = LEAKY(v); v *= BN_SCALE; }
        C16[(size_t)m_g * N + n_g] = f2bfu(v);
      }
    }
}

// ---- 64x64 NT GEMM with column-split epilogue, BK=64 ----------------------
template <int EPI1, int EPI2>
__launch_bounds__(256)
__global__ void gemm_nt64_split(const ushort_t* __restrict__ A, const ushort_t* __restrict__ B,
                                const float* __restrict__ biasPk, float* __restrict__ C32,
                                ushort_t* __restrict__ C16, int M, int N, int Kd, int Nsplit) {
  __shared__ __align__(16) ushort_t As[2][4096];
  __shared__ __align__(16) ushort_t Bs[2][4096];
  int tid = threadIdx.x;
  XCD_SWZ(64)
  GEMM64_PRE(A, B, Kd)
  f32x4 acc[2][2];
  #pragma unroll
  for (int i = 0; i < 2; ++i)
    #pragma unroll
    for (int j = 0; j < 2; ++j)
      #pragma unroll
      for (int r = 0; r < 4; ++r) acc[i][j][r] = 0.f;
  GEMM64_LOOP(Kd)
  #pragma unroll
  for (int mt = 0; mt < 2; ++mt)
    #pragma unroll
    for (int nt2 = 0; nt2 < 2; ++nt2) {
      int n_g = bn + wn + nt2 * 16 + (lane & 15);
      #pragma unroll
      for (int r = 0; r < 4; ++r) {
        int m_g = bm + wm + mt * 16 + kq * 4 + r;
        float v = acc[mt][nt2][r] + biasPk[n_g];
        if (n_g < Nsplit) {
          if (EPI1 == EPI_LEAKY) v = LEAKY(v);
          else if (EPI1 == EPI_TANH) v = tanhf(v);
        } else {
          if (EPI2 == EPI_LEAKY) v = LEAKY(v);
          else if (EPI2 == EPI_TANH) v = tanhf(v);
        }
        if (C32) C32[(size_t)m_g * N + n_g] = v;
        if (C16) C16[(size_t)m_g * N + n_g] = f2bfu(v);
      }
    }
}

// ---- X3T producer for skip1/2 (roles swapped, bitwise-identical), BK=64 ---
__launch_bounds__(256)
__global__ void gemm_w3T_z(const ushort_t* __restrict__ W3a, const ushort_t* __restrict__ W3b,
                           const float* __restrict__ b3a, const float* __restrict__ b3b,
                           const ushort_t* __restrict__ dtb, ushort_t* __restrict__ X3T) {
  const int N = 2048, Kd = 256;
  int z = blockIdx.z;
  const ushort_t* A = z ? W3b : W3a;
  const float* bias = z ? b3b : b3a;
  const ushort_t* B = dtb + (size_t)z * 2048 * 256;
  ushort_t* C = X3T + (size_t)z * 256 * 2048;
  __shared__ __align__(16) ushort_t As[2][4096];
  __shared__ __align__(16) ushort_t Bs[2][4096];
  int tid = threadIdx.x;
  XCD_SWZ(64)
  GEMM64_PRE(A, B, Kd)
  f32x4 acc[2][2];
  #pragma unroll
  for (int i = 0; i < 2; ++i)
    #pragma unroll
    for (int j = 0; j < 2; ++j)
      #pragma unroll
      for (int r = 0; r < 4; ++r) acc[i][j][r] = 0.f;
  GEMM64_LOOP(Kd)
  #pragma unroll
  for (int mt = 0; mt < 2; ++mt)
    #pragma unroll
    for (int nt2 = 0; nt2 < 2; ++nt2) {
      int n_g = bn + wn + nt2 * 16 + (lane & 15);
      #pragma unroll
      for (int r = 0; r < 4; ++r) {
        int m_g = bm + wm + mt * 16 + kq * 4 + r;
        float v = acc[mt][nt2][r] + bias[m_g];
        v = LEAKY(v); v *= BN_SCALE;
        C[(size_t)m_g * N + n_g] = f2bfu(v);
      }
    }
}

// ---- XsKs_z = Smat_z @ X3T_z^T + dt_z, BK=64 ------------------------------
__launch_bounds__(256)
__global__ void gemm_ntt_res64_z(const ushort_t* __restrict__ SmatBase,
                                 const ushort_t* __restrict__ X3T,
                                 const ushort_t* __restrict__ dtb,
                                 ushort_t* __restrict__ XsKs) {
  const int N = 256, Kd = 2048;
  int z = blockIdx.z;
  const ushort_t* A = SmatBase + (size_t)z * 2048 * 2048;
  const ushort_t* B = X3T + (size_t)z * 256 * 2048;
  const ushort_t* R = dtb + (size_t)z * 2048 * 256;
  ushort_t* C = XsKs + (size_t)z * 2048 * 256;
  __shared__ __align__(16) ushort_t As[2][4096];
  __shared__ __align__(16) ushort_t Bs[2][4096];
  int tid = threadIdx.x;
  XCD_SWZ(64)
  GEMM64_PRE(A, B, Kd)
  f32x4 acc[2][2];
  #pragma unroll
  for (int i = 0; i < 2; ++i)
    #pragma unroll
    for (int j = 0; j < 2; ++j)
      #pragma unroll
      for (int r = 0; r < 4; ++r) acc[i][j][r] = 0.f;
  GEMM64_LOOP(Kd)
  #pragma unroll
  for (int mt = 0; mt < 2; ++mt)
    #pragma unroll
    for (int nt2 = 0; nt2 < 2; ++nt2) {
      int n_g = bn + wn + nt2 * 16 + (lane & 15);
      #pragma unroll
      for (int r = 0; r < 4; ++r) {
        int m_g = bm + wm + mt * 16 + kq * 4 + r;
        float v = acc[mt][nt2][r] + bfu2f(R[(size_t)m_g * N + n_g]);
        C[(size_t)m_g * N + n_g] = f2bfu(v);
      }
    }
}

// ---- attn2 fe GEMM: A = [Bfuse | broadcast M1b], Kd=512, N=256 ------------
__launch_bounds__(256)
__global__ void gemm_fe2(const ushort_t* __restrict__ Bf, const ushort_t* __restrict__ M1b,
                         const ushort_t* __restrict__ Bw, const float* __restrict__ bias,
                         ushort_t* __restrict__ C16) {
  const int N = 256, Kd = 512;
  __shared__ __align__(16) ushort_t As[2][4096];
  __shared__ __align__(16) ushort_t Bs[2][4096];
  int tid = threadIdx.x;
  XCD_SWZ(64)
  int wave = tid >> 6, lane = tid & 63;
  int wm = (wave >> 1) * 32, wn = (wave & 1) * 32;
  int mrow = lane & 15, kq = lane >> 4;
  int c0 = wave * 128 + lane;
  int c1 = c0 + 64;
  int r0_ = (c0 >> 2) & 63, off0 = (c0 >> 8) * 32 + (c0 & 3) * 8;
  int r1_ = (c1 >> 2) & 63, off1 = (c1 >> 8) * 32 + (c1 & 3) * 8;
  const ushort_t* gb0 = Bw + (size_t)(bn + r0_) * Kd + off0;
  const ushort_t* gb1 = Bw + (size_t)(bn + r1_) * Kd + off1;

  f32x4 acc[2][2];
  #pragma unroll
  for (int i = 0; i < 2; ++i)
    #pragma unroll
    for (int j = 0; j < 2; ++j)
      #pragma unroll
      for (int r = 0; r < 4; ++r) acc[i][j][r] = 0.f;

  gload16(Bf + (size_t)(bm + r0_) * 256 + off0, &As[0][c0 * 8]);
  gload16(Bf + (size_t)(bm + r1_) * 256 + off1, &As[0][c1 * 8]);
  gload16(gb0, &Bs[0][c0 * 8]);
  gload16(gb1, &Bs[0][c1 * 8]);
  for (int t = 0; t < 8; ++t) {
    int cur = t & 1;
    __syncthreads();
    if (t + 1 < 8) {
      int tn = t + 1;
      int ko = tn * 64;
      const ushort_t* a0 = (tn < 4) ? Bf + (size_t)(bm + r0_) * 256 + ko + off0
                                    : M1b + (ko - 256) + off0;
      const ushort_t* a1 = (tn < 4) ? Bf + (size_t)(bm + r1_) * 256 + ko + off1
                                    : M1b + (ko - 256) + off1;
      gload16(a0, &As[cur ^ 1][c0 * 8]);
      gload16(a1, &As[cur ^ 1][c1 * 8]);
      gload16(gb0 + ko, &Bs[cur ^ 1][c0 * 8]);
      gload16(gb1 + ko, &Bs[cur ^ 1][c1 * 8]);
    }
    #pragma unroll
    for (int ks = 0; ks < 2; ++ks) {
      bf16x8 af[2], bf[2];
      #pragma unroll
      for (int mt = 0; mt < 2; ++mt)
        af[mt] = *(const bf16x8*)&As[cur][ks * 2048 + (wm + mt * 16 + mrow) * 32 + kq * 8];
      #pragma unroll
      for (int nt2 = 0; nt2 < 2; ++nt2)
        bf[nt2] = *(const bf16x8*)&Bs[cur][ks * 2048 + (wn + nt2 * 16 + mrow) * 32 + kq * 8];
      #pragma unroll
      for (int mt = 0; mt < 2; ++mt)
        #pragma unroll
        for (int nt2 = 0; nt2 < 2; ++nt2)
          acc[mt][nt2] = __builtin_amdgcn_mfma_f32_16x16x32_bf16(af[mt], bf[nt2], acc[mt][nt2], 0, 0, 0);
    }
  }
  #pragma unroll
  for (int mt = 0; mt < 2; ++mt)
    #pragma unroll
    for (int nt2 = 0; nt2 < 2; ++nt2) {
      int n_g = bn + wn + nt2 * 16 + (lane & 15);
      #pragma unroll
      for (int r = 0; r < 4; ++r) {
        int m_g = bm + wm + mt * 16 + kq * 4 + r;
        float v = acc[mt][nt2][r] + bias[n_g];
        v = LEAKY(v);
        C16[(size_t)m_g * N + n_g] = f2bfu(v);
      }
    }
}

// ---- split-K TN GEMM: Mm = X12m[:, :128]^T @ X12m[:, 128:] ----------------
__global__ void gemm_tn_part(const ushort_t* __restrict__ X, float* __restrict__ part) {
  int tx = threadIdx.x & 15, ty = threadIdx.x >> 4;
  int i = blockIdx.y * 16 + ty, j = blockIdx.x * 16 + tx;
  int ks = blockIdx.z;
  float acc = 0.f;
  for (int k = ks * 128; k < ks * 128 + 128; ++k)
    acc += bfu2f(X[(size_t)k * 256 + i]) * bfu2f(X[(size_t)k * 256 + 128 + j]);
  part[(size_t)ks * 16384 + i * 128 + j] = acc;
}
__global__ void gemm_tn_reduce(const float* __restrict__ part, ushort_t* __restrict__ Mm) {
  int idx = blockIdx.x * 256 + threadIdx.x;
  float s = 0.f;
  #pragma unroll
  for (int ks = 0; ks < 16; ++ks) s += part[(size_t)ks * 16384 + idx];
  Mm[idx] = f2bfu(s);
}

// ---- 2-stage column softmax (partB folded into partC) ---------------------
__global__ void smax_partA(const ushort_t* __restrict__ Sb, float* __restrict__ pm,
                           float* __restrict__ pl, int N) {
  int z = blockIdx.z;
  const ushort_t* S = Sb + (size_t)z * 2048 * 2048;
  int t = threadIdx.x;
  int col = blockIdx.x * 64 + (t & 63);
  int g = t >> 6;
  int r0 = blockIdx.y * 128 + g;
  float vals[32];
  #pragma unroll
  for (int i = 0; i < 32; ++i)
    vals[i] = bfu2f(S[(size_t)(r0 + 4 * i) * N + col]);
  float m = -1e30f;
  #pragma unroll
  for (int i = 0; i < 32; ++i) m = fmaxf(m, vals[i]);
  float l = 0.f;
  #pragma unroll
  for (int i = 0; i < 32; ++i) l += expf(vals[i] - m);
  __shared__ float rm[4][64], rl[4][64];
  rm[g][t & 63] = m; rl[g][t & 63] = l;
  __syncthreads();
  if (g == 0) {
    int c = t & 63;
    float M0 = rm[0][c], L0 = rl[0][c];
    #pragma unroll
    for (int j = 1; j < 4; ++j) {
      float Mj = rm[j][c], Lj = rl[j][c];
      float nm = fmaxf(M0, Mj);
      L0 = L0 * expf(M0 - nm) + Lj * expf(Mj - nm);
      M0 = nm;
    }
    pm[((size_t)z * 16 + blockIdx.y) * N + col] = M0;
    pl[((size_t)z * 16 + blockIdx.y) * N + col] = L0;
  }
}
__global__ void smax_partC(ushort_t* __restrict__ Sb, const float* __restrict__ pm,
                           const float* __restrict__ pl, int N) {
  int z = blockIdx.z;
  ushort_t* S = Sb + (size_t)z * 2048 * 2048;
  int t = threadIdx.x;
  int col = blockIdx.x * 64 + (t & 63);
  int g = t >> 6;
  __shared__ float sgm[64], sgi[64];
  if (t < 64) {
    float m = -1e30f, l = 0.f;
    for (int b = 0; b < 16; ++b) {
      float bm = pm[((size_t)z * 16 + b) * N + col];
      float bl = pl[((size_t)z * 16 + b) * N + col];
      float nm = fmaxf(m, bm);
      l = l * expf(m - nm) + bl * expf(bm - nm);
      m = nm;
    }
    sgm[t] = m;
    sgi[t] = 1.f / l;
  }
  __syncthreads();
  float m = sgm[t & 63], inv = sgi[t & 63];
  int r0 = blockIdx.y * 128 + g;
  #pragma unroll 8
  for (int i = 0; i < 32; ++i) {
    size_t idx = (size_t)(r0 + 4 * i) * N + col;
    S[idx] = f2bfu(expf(bfu2f(S[idx]) - m) * inv);
  }
}

// ---- row squared-norms from bf16 (2 rows/block, vectorized) ---------------
__global__ void row_norm_bf16(const ushort_t* __restrict__ X, float* __restrict__ out, int Kd) {
  int r = blockIdx.x * 2 + (threadIdx.x >> 5);
  int l = threadIdx.x & 31;
  bf16x8 v = *(const bf16x8*)&X[(size_t)r * Kd + l * 8];
  float s = 0.f;
  #pragma unroll
  for (int j = 0; j < 8; ++j) { float f = bfu2f((ushort_t)v[j]); s += f * f; }
  for (int off = 16; off; off >>= 1) s += __shfl_down(s, off, 32);
  if (l == 0) out[r] = s;
}

// ---- mask scores: 32 blocks x (64 cols x 4 h-segments), LDS reduce --------
__global__ void mask_score(const float* __restrict__ A3, const float* __restrict__ w4,
                           const float* __restrict__ b4, float* __restrict__ s) {
  __shared__ float red[4][64];
  int t = threadIdx.x;
  int col = blockIdx.x * 64 + (t & 63);
  int seg = t >> 6;
  float acc = 0.f;
  for (int h = seg * 32; h < seg * 32 + 32; ++h)
    acc += A3[(size_t)h * 2048 + col] * w4[h];
  red[seg][t & 63] = acc;
  __syncthreads();
  if (seg == 0)
    s[col] = red[0][t] + red[1][t] + red[2][t] + red[3][t] + b4[0];
}

// ---- stable descending-argsort rank via LDS-staged scores -----------------
__global__ void topk_rank(const float* __restrict__ s, int* __restrict__ idx, int K, int S) {
  __shared__ float sv[2048];
  int t = threadIdx.x;
  for (int i = t; i < K; i += 256) sv[i] = s[i];
  __syncthreads();
  int j = blockIdx.x * 256 + t;
  if (j >= K) return;
  float sj = sv[j];
  int rank = 0;
  #pragma unroll 8
  for (int i = 0; i < 2048; ++i) {
    float si = sv[i];
    rank += (si > sj) || (si == sj && i < j);
  }
  if (rank < S) idx[rank] = j;
}

// ---- build cat = [B_dt | softmax(aff_s[:,idx],axis=1) | 0pad], bf16 -------
__global__ void build_cat(const ushort_t* __restrict__ Bdt, const ushort_t* __restrict__ affs,
                          const int* __restrict__ idx, ushort_t* __restrict__ cat) {
  int r = blockIdx.x, t = threadIdx.x;
  __shared__ float vals[256];
  __shared__ float red[256];
  float v = -1e30f;
  if (t < 204) {
    int ix = idx[t];
    ix = ix < 0 ? 0 : (ix > 2047 ? 2047 : ix);
    v = bfu2f(affs[(size_t)r * 2048 + ix]);
  }
  vals[t] = v;
  red[t] = v;
  __syncthreads();
  for (int off = 128; off; off >>= 1) { if (t < off) red[t] = fmaxf(red[t], red[t + off]); __syncthreads(); }
  float m = red[0];
  __syncthreads();
  float e = (t < 204) ? expf(vals[t] - m) : 0.f;
  red[t] = e;
  __syncthreads();
  for (int off = 128; off; off >>= 1) { if (t < off) red[t] += red[t + off]; __syncthreads(); }
  float inv = 1.f / red[0];
  cat[(size_t)r * 512 + t] = Bdt[(size_t)r * 256 + t];
  cat[(size_t)r * 512 + 256 + t] = (t < 204) ? f2bfu(e * inv) : (ushort_t)0;
}

// ---- a = leaky((AV*AU) @ aww.T + awb), AVU combined [2048,256] ------------
__global__ void attn_gate(const float* __restrict__ AVU, const float* __restrict__ aww,
                          const float* __restrict__ awb, float* __restrict__ a, int n) {
  int wave = threadIdx.x >> 6, lane = threadIdx.x & 63;
  int r = blockIdx.x * 4 + wave;
  if (r >= n) return;
  float s = 0.f;
  #pragma unroll
  for (int j = 0; j < 2; ++j) {
    int d = lane + 64 * j;
    s += AVU[(size_t)r * 256 + d] * AVU[(size_t)r * 256 + 128 + d] * aww[d];
  }
  for (int off = 32; off; off >>= 1) s += __shfl_down(s, off);
  if (lane == 0) {
    float acc = s + awb[0];
    a[r] = LEAKY(acc);
  }
}

// ---- softmax write-out only (A output for attention 2) --------------------
__global__ void softmax_out(const float* __restrict__ x, float* __restrict__ y2, int n) {
  __shared__ float red[256];
  int t = threadIdx.x;
  float m = -1e30f;
  for (int i = t; i < n; i += 256) m = fmaxf(m, x[i]);
  red[t] = m;
  __syncthreads();
  for (int off = 128; off; off >>= 1) { if (t < off) red[t] = fmaxf(red[t], red[t + off]); __syncthreads(); }
  m = red[0];
  __syncthreads();
  float s = 0.f;
  for (int i = t; i < n; i += 256) s += expf(x[i] - m);
  red[t] = s;
  __syncthreads();
  for (int off = 128; off; off >>= 1) { if (t < off) red[t] += red[t + off]; __syncthreads(); }
  float inv = 1.f / red[0];
  for (int i = t; i < n; i += 256)
    y2[i] = expf(x[i] - m) * inv;
}

// ---- fused softmax + weighted column sum (64 partials) --------------------
__global__ void colsum_sm(const float* __restrict__ avec, const ushort_t* __restrict__ H,
                          float* __restrict__ part, int n) {
  __shared__ float red[256];
  int t = threadIdx.x;
  float m = -1e30f;
  for (int i = t; i < n; i += 256) m = fmaxf(m, avec[i]);
  red[t] = m;
  __syncthreads();
  for (int off = 128; off; off >>= 1) { if (t < off) red[t] = fmaxf(red[t], red[t + off]); __syncthreads(); }
  m = red[0];
  __syncthreads();
  float s = 0.f;
  for (int i = t; i < n; i += 256) s += expf(avec[i] - m);
  red[t] = s;
  __syncthreads();
  for (int off = 128; off; off >>= 1) { if (t < off) red[t] += red[t + off]; __syncthreads(); }
  float inv = 1.f / red[0];
  int bk = blockIdx.x, c = t;
  float acc = 0.f;
  for (int r = bk; r < n; r += 64)
    acc += expf(avec[r] - m) * inv * bfu2f(H[(size_t)r * 256 + c]);
  part[bk * 256 + c] = acc;
}
__global__ void colsum_fin(const float* __restrict__ part, float* __restrict__ out) {
  int c = threadIdx.x;
  float s = 0.f;
  #pragma unroll
  for (int k = 0; k < 64; ++k) s += part[k * 256 + c];
  out[c] = s;
}

// ---- gemv, one wave per output row, coalesced W reads; dual f32/bf16 out --
__global__ void gemv_act(const float* __restrict__ x, const float* __restrict__ W,
                         const float* __restrict__ b, float* __restrict__ out,
                         ushort_t* __restrict__ out16, int O, int Kd, int act) {
  int wave = threadIdx.x >> 6, lane = threadIdx.x & 63;
  int o = blockIdx.x * 4 + wave;
  if (o >= O) return;
  float s = 0.f;
  for (int c = lane; c < Kd; c += 64) s += x[c] * W[(size_t)o * Kd + c];
  for (int off = 32; off; off >>= 1) s += __shfl_down(s, off);
  if (lane == 0) {
    float acc = s + (b ? b[o] : 0.f);
    float v = act ? LEAKY(acc) : acc;
    out[o] = v;
    if (out16) out16[o] = f2bfu(v);
  }
}

// ---- final sigmoid head: prod 4-way add + shfl tree (same order as before) -
__global__ void final_sig(const float* __restrict__ a2, const float* __restrict__ clsw,
                          const float* __restrict__ clsb, float* __restrict__ Yout) {
  __shared__ float prod[256];
  int t = threadIdx.x;
  if (t < 256) prod[t] = a2[t] * clsw[t];
  __syncthreads();
  if (t < 64) {
    float s = prod[t] + prod[t + 64] + prod[t + 128] + prod[t + 192];
    for (int off = 32; off; off >>= 1) s += __shfl_down(s, off);
    if (t == 0) {
      float y = s + clsb[0];
      y = 1.f / (1.f + expf(-y));
      y = fminf(fmaxf(y, 1e-5f), 1.f - 1e-5f);
      Yout[0] = y;
    }
  }
}

extern "C" void kernel_launch(void* const* d_in, const int* in_sizes, int n_in,
                              void* d_out, int out_size, void* d_ws, size_t ws_size,
                              hipStream_t stream) {
  auto IN = [&](int i) { return (const float*)d_in[i]; };
  (void)n_in; (void)in_sizes; (void)out_size;

  const int S = 204;
  float* out_f = (float*)d_out;

  float* W = (float*)d_ws;
  size_t off = 0;
  auto F = [&](size_t n) { float* p = W + off; off += n; return p; };
  auto FU = [&](size_t nus) { return (ushort_t*)F((nus + 1) / 2); };

  ushort_t* dt_b  = FU((size_t)4096 * 256);   // B_dt | KB_dt
  ushort_t* XsKs  = FU((size_t)4096 * 256);   // Xs | Ks
  ushort_t* X12b  = FU((size_t)4096 * 256);   // skip12 X1|X2 (also skip3 X12, mask X12m)
  ushort_t* X3sb  = FU((size_t)4096 * 256);   // skip12 X3T both z: [2][256][2048]
  ushort_t* aff_b = FU((size_t)2048 * 2048);
  float* AVU   = F((size_t)2048 * 256);
  ushort_t* Mm_b = FU((size_t)128 * 128);
  ushort_t* M1b  = FU(256);
  float* svec  = F(2048);
  int*   idxb  = (int*)F(256);
  float* avec  = F(2048);
  float* AH    = F(256);
  float* M1v   = F(256);
  float* AH2   = F(256);
  float* bvec_ws = F(512);
  float* a2_ws   = F(256);
  float* nxy   = F(4096);
  float* part  = F(16384);
  float* sm_pm = F((size_t)2 * 16 * 2048);
  float* sm_pl = F((size_t)2 * 16 * 2048);
  float* pbias = F(6 * 256);                  // packed: sk1, sk2, sk3, mask, a1vu, a2vu
  off = (off + 3) & ~(size_t)3;               // 16B align for h1g uint4 dump
  ushort_t* h1g = FU((size_t)2048 * 6912 + 1280);  // conv1->conv2 h1T, +slack

  // bf16 weight arena
  size_t wo = 0;
  ushort_t* warena = (ushort_t*)F(3250000);
  auto WA = [&](size_t n) { ushort_t* p = warena + wo; wo = (wo + n + 15) & ~(size_t)15; return p; };
  ushort_t* w2p   = WA(40960);                 // conv2 relayout [64][640]
  ushort_t* embp  = WA(212992);                // embed weight padded [256][832]
  ushort_t* s1w1 = WA(32768); ushort_t* s1w2 = WA(32768); ushort_t* s1w3 = WA(65536);
  ushort_t* s2w1 = WA(32768); ushort_t* s2w2 = WA(32768); ushort_t* s2w3 = WA(65536);
  ushort_t* s3w1 = WA(262144); ushort_t* s3w2 = WA(262144); ushort_t* s3w3 = WA(4194304);
  ushort_t* mw1 = WA(262144); ushort_t* mw2 = WA(262144); ushort_t* mw3 = WA(262144);
  ushort_t* fwp = WA(131072);
  ushort_t* a1fe = WA(65536); ushort_t* a1v = WA(32768); ushort_t* a1u = WA(32768);
  ushort_t* a2fe = WA(131072); ushort_t* a2v = WA(32768); ushort_t* a2u = WA(32768);
  (void)s1w2; (void)s2w2; (void)s3w2; (void)mw2; (void)a1u; (void)a2u;

  float* pool = F((size_t)4194304);           // 16 MB phase-shared

  const size_t NEED_BYTES = off * 4;
  if (ws_size < NEED_BYTES) {
    fill_out<<<9, 256, 0, stream>>>(out_f, 2049);
    return;
  }

  // pool phases
  ushort_t* h2h_b   = (ushort_t*)pool;               // conv: 4096*832 us
  ushort_t* SmatB   = (ushort_t*)pool;               // skip12: 2 x 2048^2 us (16MB)
  ushort_t* X3b_b   = (ushort_t*)(pool + 2097152);   // skip3: X3T 2048*2048 us
  float* A3   = pool;                                // mask: 128*2048 f
  float* tnpt = pool + 262144;                       // mask: 16*16384 f
  ushort_t* cat_b   = (ushort_t*)pool;               // fuse: 2048*512 us
  ushort_t* Bfuse_b = (ushort_t*)(pool + 1048576);
  ushort_t* Hbuf_b  = (ushort_t*)(pool + 1310720);

  // ---- weight conversion + packing ----
  CvtArgs ca;
  const float* srcs[20] = { IN(6), IN(8), IN(10), IN(12), IN(14), IN(16), IN(18),
                            IN(20), IN(22), IN(24), IN(26), IN(28), IN(30),
                            IN(36), IN(38), IN(40), IN(46), IN(48), IN(50), IN(4) };
  ushort_t* dsts[20] = { nullptr, s1w1, s1w2, s1w3, s2w1, s2w2, s2w3,
                         s3w1, s3w2, s3w3, mw1, mw2, mw3,
                         a1fe, a1v, a1u, a2fe, a2v, a2u, w2p };
  int lens[20] = { 0, 32768, 32768, 65536, 32768, 32768, 65536,
                   262144, 262144, 4194304, 262144, 262144, 262144,
                   65536, 32768, 32768, 131072, 32768, 32768, 0 };
  int cum = 0;
  for (int i = 0; i < 20; ++i) {
    ca.src[i] = srcs[i]; ca.dst[i] = dsts[i] ? dsts[i] : w2p;
    ca.cum[i] = cum; cum += lens[i];
  }
  ca.cum[20] = cum;
  to_bf16_flat<<<2048, 256, 0, stream>>>(ca);
  w2_relayout<<<160, 256, 0, stream>>>(IN(4), w2p);
  pad_rows_bf16<<<512, 256, 0, stream>>>(IN(34), fwp, 256, 460, 512);
  pad_rows_bf16<<<832, 256, 0, stream>>>(IN(6), embp, 256, 800, 832);
  BiasPk bp;
  const float* bsrc[12] = { IN(9), IN(11), IN(15), IN(17), IN(21), IN(23),
                            IN(27), IN(29), IN(39), IN(41), IN(49), IN(51) };
  for (int i = 0; i < 12; ++i) bp.a[i] = bsrc[i];
  bp.out = pbias;
  bias_pack<<<6, 256, 0, stream>>>(bp);
  float* pb_sk1 = pbias, *pb_sk2 = pbias + 256, *pb_sk3 = pbias + 512;
  float* pb_msk = pbias + 768, *pb_a1 = pbias + 1024, *pb_a2 = pbias + 1280;

  // ---- conv (split) + embedding ----
  conv1_pool<<<2048, 256, 0, stream>>>(IN(0), IN(1), IN(2), IN(3), h1g);
  conv2_mfma<<<2048, 256, 0, stream>>>(h1g, w2p, IN(5), h2h_b);
  gemm_bf16_nt64<EPI_LEAKY><<<dim3(4, 64), 256, 0, stream>>>(
      h2h_b, embp, IN(7), nullptr, dt_b, 4096, 256, 832);

  // ---- skip1+skip2, both branches fused (X3 produced transposed) ----
  gemm_nt64_dual<EPI_LEAKY_BN><<<dim3(4, 64), 256, 0, stream>>>(
      dt_b, s1w1, s2w1, pb_sk1, pb_sk2, X12b, 4096, 256, 256, 2048);
  gemm_w3T_z<<<dim3(32, 4, 2), 256, 0, stream>>>(s1w3, s2w3, IN(13), IN(19), dt_b, X3sb);
  gemm_smat_z<<<dim3(16, 16, 2), 256, 0, stream>>>(X12b, SmatB);
  smax_partA<<<dim3(32, 16, 2), 256, 0, stream>>>(SmatB, sm_pm, sm_pl, 2048);
  smax_partC<<<dim3(32, 16, 2), 256, 0, stream>>>(SmatB, sm_pm, sm_pl, 2048);
  gemm_ntt_res64_z<<<dim3(4, 32, 2), 256, 0, stream>>>(SmatB, X3sb, dt_b, XsKs);

  // ---- euclid -> aff_b ----
  row_norm_bf16<<<2048, 64, 0, stream>>>(XsKs, nxy, 256);
  gemm_bf16_nt<EPI_EUCLID><<<dim3(16, 16), 256, 0, stream>>>(
      XsKs, XsKs + (size_t)2048 * 256, nullptr, nullptr, aff_b, 2048, 2048, 256,
      nxy, nxy + 2048);

  // ---- skip3 (aff in-place; X3 produced transposed -> both big GEMMs NT) ----
  gemm_bf16_nt64<EPI_LEAKY_BN><<<dim3(4, 32), 256, 0, stream>>>(
      aff_b, s3w1, pb_sk3, nullptr, X12b, 2048, 256, 2048);
  gemm_smat_z<<<dim3(16, 16, 1), 256, 0, stream>>>(X12b, SmatB);
  gemm_bf16_nt<EPI_LEAKY_BN_ROW><<<dim3(16, 16), 256, 0, stream>>>(
      s3w3, aff_b, IN(25), nullptr, X3b_b, 2048, 2048, 2048, nullptr, nullptr);
  smax_partA<<<dim3(32, 16, 1), 256, 0, stream>>>(SmatB, sm_pm, sm_pl, 2048);
  smax_partC<<<dim3(32, 16, 1), 256, 0, stream>>>(SmatB, sm_pm, sm_pl, 2048);
  gemm_bf16_nt<EPI_RES><<<dim3(16, 16), 256, 0, stream>>>(
      SmatB, X3b_b, nullptr, nullptr, aff_b, 2048, 2048, 2048,
      (const float*)aff_b, nullptr);
  ushort_t* affs_b = aff_b;

  // ---- mask_scores -> top-S idx ----
  gemm_nt64_split<EPI_LEAKY, EPI_TANH><<<dim3(4, 32), 256, 0, stream>>>(
      affs_b, mw1, pb_msk, nullptr, X12b, 2048, 256, 2048, 128);
  gemm_tn_part<<<dim3(8, 8, 16), 256, 0, stream>>>(X12b, tnpt);
  gemm_tn_reduce<<<64, 256, 0, stream>>>(tnpt, Mm_b);
  gemm_bf16_nt64<EPI_LEAKY><<<dim3(32, 2), 256, 0, stream>>>(
      Mm_b, mw3, IN(31), A3, nullptr, 128, 2048, 128);
  mask_score<<<32, 256, 0, stream>>>(A3, IN(32), IN(33), svec);
  topk_rank<<<8, 256, 0, stream>>>(svec, idxb, 2048, S);

  // ---- B_bag + concat + fuse ----
  build_cat<<<2048, 256, 0, stream>>>(dt_b, affs_b, idxb, cat_b);
  gemm_bf16_nt64<EPI_LEAKY><<<dim3(4, 32), 256, 0, stream>>>(
      cat_b, fwp, IN(35), nullptr, Bfuse_b, 2048, 256, 512);

  // ---- attention 1 ----
  gemm_bf16_nt64<EPI_LEAKY><<<dim3(4, 32), 256, 0, stream>>>(
      Bfuse_b, a1fe, IN(37), nullptr, Hbuf_b, 2048, 256, 256);
  gemm_nt64_split<EPI_TANH, EPI_LEAKY><<<dim3(4, 32), 256, 0, stream>>>(
      Hbuf_b, a1v, pb_a1, AVU, nullptr, 2048, 256, 256, 128);
  attn_gate<<<512, 256, 0, stream>>>(AVU, IN(42), IN(43), avec, 2048);
  colsum_sm<<<64, 256, 0, stream>>>(avec, Hbuf_b, part, 2048);
  colsum_fin<<<1, 256, 0, stream>>>(part, AH);
  gemv_act<<<64, 256, 0, stream>>>(AH, IN(44), IN(45), M1v, M1b, 256, 256, 1);

  // ---- attention 2 (A -> output); A-operand streamed from [Bfuse | M1b] ----
  gemm_fe2<<<dim3(4, 32), 256, 0, stream>>>(Bfuse_b, M1b, a2fe, IN(47), Hbuf_b);
  gemm_nt64_split<EPI_TANH, EPI_LEAKY><<<dim3(4, 32), 256, 0, stream>>>(
      Hbuf_b, a2v, pb_a2, AVU, nullptr, 2048, 256, 256, 128);
  attn_gate<<<512, 256, 0, stream>>>(AVU, IN(52), IN(53), avec, 2048);
  softmax_out<<<1, 256, 0, stream>>>(avec, out_f + 1, 2048);
  colsum_sm<<<64, 256, 0, stream>>>(avec, Hbuf_b, part, 2048);
  colsum_fin<<<1, 256, 0, stream>>>(part, AH2);

  // ---- final head: parallel gemvs + tiny sigmoid (same summation order) ----
  gemv_act<<<128, 256, 0, stream>>>(AH2, IN(54), IN(55), bvec_ws, nullptr, 512, 256, 1);
  gemv_act<<<64, 256, 0, stream>>>(bvec_ws, IN(56), IN(57), a2_ws, nullptr, 256, 512, 1);
  final_sig<<<1, 256, 0, stream>>>(a2_ws, IN(58), IN(59), out_f);
}

// Round 13
// 745.942 us; speedup vs baseline: 1.1924x; 1.1924x over previous
//
#include <hip/hip_runtime.h>
#include <math.h>

#define LEAKY(x) ((x) > 0.f ? (x) : 0.01f * (x))
static constexpr float BN_SCALE = 0.9999950000374997f;

typedef unsigned short ushort_t;
typedef float f32x4 __attribute__((ext_vector_type(4)));
typedef short bf16x8 __attribute__((ext_vector_type(8)));

__device__ __forceinline__ ushort_t f2bfu(float f) {
  union { float f; unsigned u; } v; v.f = f;
  unsigned r = v.u + 0x7fffu + ((v.u >> 16) & 1u);
  return (ushort_t)(r >> 16);
}
__device__ __forceinline__ float bfu2f(ushort_t u) {
  union { unsigned u; float f; } v; v.u = ((unsigned)u) << 16;
  return v.f;
}

// ---- async global->LDS, 16B per lane (dest = wave-uniform base + lane*16) --
__device__ __forceinline__ void gload16(const ushort_t* g, ushort_t* lds) {
  __builtin_amdgcn_global_load_lds(
      (const __attribute__((address_space(1))) void*)g,
      (__attribute__((address_space(3))) void*)lds, 16, 0, 0);
}

__global__ void fill_out(float* out, int n) {
  int i = blockIdx.x * 256 + threadIdx.x;
  if (i < n) out[i] = 0.25f;
}

// ---- one-shot fp32 -> bf16 conversion, flat-indexed over all tensors ------
struct CvtArgs {
  const float* src[20];
  ushort_t* dst[20];
  int cum[21];
};
__global__ void to_bf16_flat(CvtArgs a) {
  int total = a.cum[20];
  for (int i = blockIdx.x * 256 + threadIdx.x; i < total; i += gridDim.x * 256) {
    int s = 0;
    while (i >= a.cum[s + 1]) ++s;
    int off = i - a.cum[s];
    a.dst[s][off] = f2bfu(a.src[s][off]);
  }
}

// ---- pack 6 bias pairs [128|128] -> fp32 [6][256] -------------------------
struct BiasPk { const float* a[12]; float* out; };
__global__ void bias_pack(BiasPk p) {
  int b = blockIdx.x, t = threadIdx.x;
  p.out[b * 256 + t] = (t < 128) ? p.a[2 * b][t] : p.a[2 * b + 1][t - 128];
}

// ---- generic row pad: fp32 [O][Kin] -> bf16 [O][Kpad] with zero fill ------
__global__ void pad_rows_bf16(const float* __restrict__ w, ushort_t* __restrict__ wp,
                              int O, int Kin, int Kpad) {
  int idx = blockIdx.x * 256 + threadIdx.x;
  if (idx >= O * Kpad) return;
  int o = idx / Kpad, k = idx - o * Kpad;
  wp[idx] = (k < Kin) ? f2bfu(w[(size_t)o * Kin + k]) : (ushort_t)0;
}

// ---- conv2 weight relayout: w2[50][20][25] -> w2p[64][tap*24+ic] bf16 -----
__global__ void w2_relayout(const float* __restrict__ w2, ushort_t* __restrict__ w2p) {
  int idx = blockIdx.x * 256 + threadIdx.x;  // 64*640
  if (idx >= 64 * 640) return;
  int oc = idx / 640, k = idx - oc * 640;
  int tap = k / 24, ic = k - tap * 24;
  float v = 0.f;
  if (oc < 50 && tap < 25 && ic < 20)
    v = w2[(size_t)(oc * 20 + ic) * 25 + tap];
  w2p[idx] = f2bfu(v);
}

// ---- XCD-aware bijective block swizzle (grid size divisible by 8) ---------
#define XCD_SWZ(TILE)                                                          \
  int id_ = blockIdx.y * gridDim.x + blockIdx.x;                               \
  int nwg_ = gridDim.x * gridDim.y;                                            \
  int sw_ = (id_ & 7) * (nwg_ >> 3) + (id_ >> 3);                              \
  int bm = (sw_ / gridDim.x) * (TILE), bn = (sw_ % gridDim.x) * (TILE);

// ============================================================================
// Fused conv1+pool+conv2+pool via MFMA implicit GEMM. 2 images/block.
// Phase A item decode: cg in LOW 2 bits (5 ch/item, VGPR ~124 -> 2+ blocks/CU).
// Plain stride-32 simg (broadcast groups make reads conflict-free unswizzled).
// Output stride 832 (zero-padded 800->832) so the embed GEMM can use BK=64.
// [Split conv1/conv2 variant measured 1.9x SLOWER (r12): phase-A patch regs
//  dominate VGPR either way, and the 2x27MB h1T round-trip adds ~60us. Keep
//  fused.]
// ============================================================================
__launch_bounds__(256)
__global__ void conv12_mfma(const float* __restrict__ imgB, const float* __restrict__ imgK,
                            const float* __restrict__ w1, const float* __restrict__ b1,
                            const ushort_t* __restrict__ w2p, const float* __restrict__ b2,
                            ushort_t* __restrict__ out832) {
  __shared__ __align__(16) char smem[34816];
  ushort_t* h1T = (ushort_t*)smem;               // [0,13824): 2*144*24 ushort
  ushort_t* Bs  = (ushort_t*)(smem + 13824);     // 64*72 us
  float* simg = (float*)(smem + 13824);          // 7168 (phase A only)
  float* sw1  = (float*)(smem + 20992);
  float* b1s  = (float*)(smem + 22992);
  float* Cf   = (float*)smem;                    // epilogue

  int tid = threadIdx.x;
  int bx = blockIdx.x;
  const float* imgb = (bx < 1024) ? imgB + (size_t)bx * 2 * 784
                                  : imgK + (size_t)(bx - 1024) * 2 * 784;

  for (int i = tid; i < 1568; i += 256) {
    int im = (i >= 784) ? 1 : 0;
    int r = i - im * 784;
    int row = r / 28, col = r - row * 28;
    simg[im * 896 + row * 32 + col] = imgb[i];
  }
  for (int i = tid; i < 500; i += 256) sw1[i] = w1[i];
  if (tid < 20) b1s[tid] = b1[tid];
  for (int i = tid; i < 288; i += 256) {
    uint2 z; z.x = 0; z.y = 0;
    *(uint2*)&h1T[i * 24 + 20] = z;
  }

  int sB_r = tid >> 2;
  int sB_j0 = (tid & 3) * 2;
  bf16x8 wreg[2];
  #pragma unroll
  for (int i = 0; i < 2; ++i)
    wreg[i] = *(const bf16x8*)&w2p[(size_t)sB_r * 640 + (sB_j0 + i) * 8];

  __syncthreads();

  // phase A: cg in low 2 bits of the item index (5 channels per item)
  for (int o = tid; o < 1152; o += 256) {
    int im = (o >= 576) ? 1 : 0;
    int rem = o - im * 576;
    int cg = rem & 3;
    int pos = rem >> 2;
    int py = pos / 12, px = pos - py * 12;
    int y0 = py * 2, x0 = px * 2;
    float p[6][6];
    #pragma unroll
    for (int yy = 0; yy < 6; ++yy) {
      const float* rb = &simg[im * 896 + (y0 + yy) * 32 + x0];
      #pragma unroll
      for (int xx = 0; xx < 6; ++xx)
        p[yy][xx] = rb[xx];
    }
    #pragma unroll
    for (int cc = 0; cc < 5; ++cc) {
      int c = cg * 5 + cc;
      const float* wc = &sw1[c * 25];
      float bb = b1s[c];
      float t0 = bb, t1 = bb, t2 = bb, t3 = bb;
      #pragma unroll
      for (int ky = 0; ky < 5; ++ky)
        #pragma unroll
        for (int kx = 0; kx < 5; ++kx) {
          float wv = wc[ky * 5 + kx];
          t0 += p[ky][kx] * wv;
          t1 += p[ky][kx + 1] * wv;
          t2 += p[ky + 1][kx] * wv;
          t3 += p[ky + 1][kx + 1] * wv;
        }
      float mx = fmaxf(fmaxf(t0, t1), fmaxf(t2, t3));
      h1T[(im * 144 + pos) * 24 + c] = f2bfu(LEAKY(mx));
    }
  }

  int wave = tid >> 6, lane = tid & 63;
  int wm = (wave >> 1) * 64, wn = (wave & 1) * 32;
  int mrow = lane & 15, kq = lane >> 4;

  int imv[4], oyv[4], oxv[4];
  #pragma unroll
  for (int mt = 0; mt < 4; ++mt) {
    int r = wm + mt * 16 + mrow;
    imv[mt] = r >> 6;
    int op = r & 63;
    oyv[mt] = op >> 3;
    oxv[mt] = op & 7;
  }

  f32x4 acc[4][2];
  #pragma unroll
  for (int i = 0; i < 4; ++i)
    #pragma unroll
    for (int j = 0; j < 2; ++j)
      #pragma unroll
      for (int r = 0; r < 4; ++r) acc[i][j][r] = 0.f;

  for (int kb = 0; kb < 10; ++kb) {
    __syncthreads();
    #pragma unroll
    for (int i = 0; i < 2; ++i)
      *(bf16x8*)&Bs[sB_r * 72 + (sB_j0 + i) * 8] = wreg[i];
    if (kb + 1 < 10) {
      #pragma unroll
      for (int i = 0; i < 2; ++i)
        wreg[i] = *(const bf16x8*)&w2p[(size_t)sB_r * 640 + (kb + 1) * 64 + (sB_j0 + i) * 8];
    }
    __syncthreads();
    #pragma unroll
    for (int ks = 0; ks < 2; ++ks) {
      int g = kb * 8 + ks * 4 + kq;
      int tap = g / 3;
      int part = g - tap * 3;
      int tc = tap < 25 ? tap : 24;
      int ky = tc / 5, kx = tc - ky * 5;
      bf16x8 af[4], bf[2];
      #pragma unroll
      for (int mt = 0; mt < 4; ++mt) {
        int pos = (oyv[mt] + ky) * 12 + oxv[mt] + kx;
        af[mt] = *(const bf16x8*)&h1T[(imv[mt] * 144 + pos) * 24 + part * 8];
      }
      #pragma unroll
      for (int nt = 0; nt < 2; ++nt)
        bf[nt] = *(const bf16x8*)&Bs[(wn + nt * 16 + mrow) * 72 + ks * 32 + kq * 8];
      #pragma unroll
      for (int mt = 0; mt < 4; ++mt)
        #pragma unroll
        for (int nt = 0; nt < 2; ++nt)
          acc[mt][nt] = __builtin_amdgcn_mfma_f32_16x16x32_bf16(af[mt], bf[nt], acc[mt][nt], 0, 0, 0);
    }
  }
  __syncthreads();
  #pragma unroll
  for (int mt = 0; mt < 4; ++mt)
    #pragma unroll
    for (int nt = 0; nt < 2; ++nt) {
      int n0 = wn + nt * 16 + (lane & 15);
      #pragma unroll
      for (int r = 0; r < 4; ++r)
        Cf[(wm + mt * 16 + kq * 4 + r) * 68 + n0] = acc[mt][nt][r];
    }
  __syncthreads();
  for (int o = tid; o < 1664; o += 256) {
    int im = o / 832, oi = o - im * 832;
    ushort_t val = 0;
    if (oi < 800) {
      int oc = oi >> 4, p = oi & 15, py = p >> 2, px = p & 3;
      int r0 = im * 64 + py * 16 + px * 2;
      float bb = b2[oc];
      float t0 = LEAKY(Cf[r0 * 68 + oc] + bb);
      float t1 = LEAKY(Cf[(r0 + 1) * 68 + oc] + bb);
      float t2 = LEAKY(Cf[(r0 + 8) * 68 + oc] + bb);
      float t3 = LEAKY(Cf[(r0 + 9) * 68 + oc] + bb);
      val = f2bfu(fmaxf(fmaxf(t0, t1), fmaxf(t2, t3)));
    }
    out832[(size_t)(bx * 2 + im) * 832 + oi] = val;
  }
}

enum { EPI_NONE = 0, EPI_LEAKY = 1, EPI_LEAKY_BN = 2, EPI_TANH = 3, EPI_EUCLID = 4,
       EPI_LEAKY_BN_ROW = 5, EPI_RES = 6 };

// ---- 128x128 bf16 NT GEMM, BK=64, pipelined gloads, XCD swizzle -----------
template <int EPI>
__launch_bounds__(256)
__global__ void gemm_bf16_nt(const ushort_t* __restrict__ A, const ushort_t* __restrict__ B,
                             const float* __restrict__ bias, float* __restrict__ C32,
                             ushort_t* __restrict__ C16, int M, int N, int Kd,
                             const float* __restrict__ e1, const float* __restrict__ e2) {
  __shared__ __align__(16) ushort_t As[2][8192];
  __shared__ __align__(16) ushort_t Bs[2][8192];
  int tid = threadIdx.x;
  XCD_SWZ(128)
  int wave = tid >> 6, lane = tid & 63;
  int wm = (wave >> 1) * 64, wn = (wave & 1) * 64;
  int mrow = lane & 15, kq = lane >> 4;
  int cc[4];
  const ushort_t* ga[4];
  const ushort_t* gb[4];
  #pragma unroll
  for (int q = 0; q < 4; ++q) {
    int c = (wave * 4 + q) * 64 + lane;
    cc[q] = c;
    int row = (c >> 2) & 127, sl = c >> 9, j = c & 3;
    ga[q] = A + (size_t)(bm + row) * Kd + sl * 32 + j * 8;
    gb[q] = B + (size_t)(bn + row) * Kd + sl * 32 + j * 8;
  }

  f32x4 acc[4][4];
  #pragma unroll
  for (int i = 0; i < 4; ++i)
    #pragma unroll
    for (int j = 0; j < 4; ++j)
      #pragma unroll
      for (int r = 0; r < 4; ++r) acc[i][j][r] = 0.f;

  #pragma unroll
  for (int q = 0; q < 4; ++q) {
    gload16(ga[q], &As[0][cc[q] * 8]);
    gload16(gb[q], &Bs[0][cc[q] * 8]);
  }
  int nt = Kd >> 6;
  for (int t = 0; t < nt; ++t) {
    int cur = t & 1;
    __syncthreads();
    if (t + 1 < nt) {
      int ko = (t + 1) * 64;
      #pragma unroll
      for (int q = 0; q < 4; ++q) {
        gload16(ga[q] + ko, &As[cur ^ 1][cc[q] * 8]);
        gload16(gb[q] + ko, &Bs[cur ^ 1][cc[q] * 8]);
      }
    }
    #pragma unroll
    for (int ks = 0; ks < 2; ++ks) {
      bf16x8 af[4], bf[4];
      #pragma unroll
      for (int mt = 0; mt < 4; ++mt)
        af[mt] = *(const bf16x8*)&As[cur][ks * 4096 + (wm + mt * 16 + mrow) * 32 + kq * 8];
      #pragma unroll
      for (int nt2 = 0; nt2 < 4; ++nt2)
        bf[nt2] = *(const bf16x8*)&Bs[cur][ks * 4096 + (wn + nt2 * 16 + mrow) * 32 + kq * 8];
      #pragma unroll
      for (int mt = 0; mt < 4; ++mt)
        #pragma unroll
        for (int nt2 = 0; nt2 < 4; ++nt2)
          acc[mt][nt2] = __builtin_amdgcn_mfma_f32_16x16x32_bf16(af[mt], bf[nt2], acc[mt][nt2], 0, 0, 0);
    }
  }
  #pragma unroll
  for (int mt = 0; mt < 4; ++mt)
    #pragma unroll
    for (int nt2 = 0; nt2 < 4; ++nt2) {
      int n_g = bn + wn + nt2 * 16 + (lane & 15);
      #pragma unroll
      for (int r = 0; r < 4; ++r) {
        int m_g = bm + wm + mt * 16 + kq * 4 + r;
        float v = acc[mt][nt2][r];
        if (EPI == EPI_EUCLID) {
          v = e1[m_g] + e2[n_g] - 2.f * v;
          v = sqrtf(fmaxf(v, 0.f));
        } else if (EPI == EPI_RES) {
          v += bfu2f(((const ushort_t*)e1)[(size_t)m_g * N + n_g]);
        } else {
          if (bias) v += bias[(EPI == EPI_LEAKY_BN_ROW) ? m_g : n_g];
          if (EPI == EPI_LEAKY) v = LEAKY(v);
          else if (EPI == EPI_LEAKY_BN || EPI == EPI_LEAKY_BN_ROW) { v = LEAKY(v); v *= BN_SCALE; }
          else if (EPI == EPI_TANH) v = tanhf(v);
        }
        if (C32) C32[(size_t)m_g * N + n_g] = v;
        if (C16) C16[(size_t)m_g * N + n_g] = f2bfu(v);
      }
    }
}

// ---- Smat z-GEMM: Smat_z = X12_z[:, :128] @ X12_z[:, 128:]^T, BK=64 -------
__launch_bounds__(256)
__global__ void gemm_smat_z(const ushort_t* __restrict__ X12, ushort_t* __restrict__ Smat) {
  int z = blockIdx.z;
  const ushort_t* A = X12 + (size_t)z * 2048 * 256;
  const ushort_t* B = A + 128;
  ushort_t* C = Smat + (size_t)z * 2048 * 2048;
  __shared__ __align__(16) ushort_t As[2][8192];
  __shared__ __align__(16) ushort_t Bs[2][8192];
  int tid = threadIdx.x;
  XCD_SWZ(128)
  int wave = tid >> 6, lane = tid & 63;
  int wm = (wave >> 1) * 64, wn = (wave & 1) * 64;
  int mrow = lane & 15, kq = lane >> 4;
  int cc[4];
  const ushort_t* ga[4];
  const ushort_t* gb[4];
  #pragma unroll
  for (int q = 0; q < 4; ++q) {
    int c = (wave * 4 + q) * 64 + lane;
    cc[q] = c;
    int row = (c >> 2) & 127, sl = c >> 9, j = c & 3;
    ga[q] = A + (size_t)(bm + row) * 256 + sl * 32 + j * 8;
    gb[q] = B + (size_t)(bn + row) * 256 + sl * 32 + j * 8;
  }

  f32x4 acc[4][4];
  #pragma unroll
  for (int i = 0; i < 4; ++i)
    #pragma unroll
    for (int j = 0; j < 4; ++j)
      #pragma unroll
      for (int r = 0; r < 4; ++r) acc[i][j][r] = 0.f;

  #pragma unroll
  for (int q = 0; q < 4; ++q) {
    gload16(ga[q], &As[0][cc[q] * 8]);
    gload16(gb[q], &Bs[0][cc[q] * 8]);
  }
  for (int t = 0; t < 2; ++t) {
    int cur = t & 1;
    __syncthreads();
    if (t + 1 < 2) {
      int ko = (t + 1) * 64;
      #pragma unroll
      for (int q = 0; q < 4; ++q) {
        gload16(ga[q] + ko, &As[cur ^ 1][cc[q] * 8]);
        gload16(gb[q] + ko, &Bs[cur ^ 1][cc[q] * 8]);
      }
    }
    #pragma unroll
    for (int ks = 0; ks < 2; ++ks) {
      bf16x8 af[4], bf[4];
      #pragma unroll
      for (int mt = 0; mt < 4; ++mt)
        af[mt] = *(const bf16x8*)&As[cur][ks * 4096 + (wm + mt * 16 + mrow) * 32 + kq * 8];
      #pragma unroll
      for (int nt2 = 0; nt2 < 4; ++nt2)
        bf[nt2] = *(const bf16x8*)&Bs[cur][ks * 4096 + (wn + nt2 * 16 + mrow) * 32 + kq * 8];
      #pragma unroll
      for (int mt = 0; mt < 4; ++mt)
        #pragma unroll
        for (int nt2 = 0; nt2 < 4; ++nt2)
          acc[mt][nt2] = __builtin_amdgcn_mfma_f32_16x16x32_bf16(af[mt], bf[nt2], acc[mt][nt2], 0, 0, 0);
    }
  }
  #pragma unroll
  for (int mt = 0; mt < 4; ++mt)
    #pragma unroll
    for (int nt2 = 0; nt2 < 4; ++nt2) {
      int n_g = bn + wn + nt2 * 16 + (lane & 15);
      #pragma unroll
      for (int r = 0; r < 4; ++r) {
        int m_g = bm + wm + mt * 16 + kq * 4 + r;
        C[(size_t)m_g * 2048 + n_g] = f2bfu(acc[mt][nt2][r]);
      }
    }
}

// ---- 64x64 family BK=64 staging macro body (bm/bn set by caller) ----------
#define GEMM64_PRE(Aptr, Bptr, KD)                                             \
  int wave = tid >> 6, lane = tid & 63;                                        \
  int wm = (wave >> 1) * 32, wn = (wave & 1) * 32;                             \
  int mrow = lane & 15, kq = lane >> 4;                                        \
  int c0 = wave * 128 + lane;                                                  \
  int c1 = c0 + 64;                                                            \
  int r0_ = (c0 >> 2) & 63, s0_ = c0 >> 8, j0_ = c0 & 3;                       \
  int r1_ = (c1 >> 2) & 63, s1_ = c1 >> 8, j1_ = c1 & 3;                       \
  const ushort_t* ga0 = Aptr + (size_t)(bm + r0_) * KD + s0_ * 32 + j0_ * 8;   \
  const ushort_t* ga1 = Aptr + (size_t)(bm + r1_) * KD + s1_ * 32 + j1_ * 8;   \
  const ushort_t* gb0 = Bptr + (size_t)(bn + r0_) * KD + s0_ * 32 + j0_ * 8;   \
  const ushort_t* gb1 = Bptr + (size_t)(bn + r1_) * KD + s1_ * 32 + j1_ * 8;

#define GEMM64_LOOP(KD)                                                        \
  gload16(ga0, &As[0][c0 * 8]);                                                \
  gload16(ga1, &As[0][c1 * 8]);                                                \
  gload16(gb0, &Bs[0][c0 * 8]);                                                \
  gload16(gb1, &Bs[0][c1 * 8]);                                                \
  int ntile = (KD) >> 6;                                                       \
  for (int t = 0; t < ntile; ++t) {                                            \
    int cur = t & 1;                                                           \
    __syncthreads();                                                           \
    if (t + 1 < ntile) {                                                       \
      int ko = (t + 1) * 64;                                                   \
      gload16(ga0 + ko, &As[cur ^ 1][c0 * 8]);                                 \
      gload16(ga1 + ko, &As[cur ^ 1][c1 * 8]);                                 \
      gload16(gb0 + ko, &Bs[cur ^ 1][c0 * 8]);                                 \
      gload16(gb1 + ko, &Bs[cur ^ 1][c1 * 8]);                                 \
    }                                                                          \
    _Pragma("unroll")                                                          \
    for (int ks = 0; ks < 2; ++ks) {                                           \
      bf16x8 af[2], bf[2];                                                     \
      _Pragma("unroll")                                                        \
      for (int mt = 0; mt < 2; ++mt)                                           \
        af[mt] = *(const bf16x8*)&As[cur][ks * 2048 + (wm + mt * 16 + mrow) * 32 + kq * 8]; \
      _Pragma("unroll")                                                        \
      for (int nt2 = 0; nt2 < 2; ++nt2)                                        \
        bf[nt2] = *(const bf16x8*)&Bs[cur][ks * 2048 + (wn + nt2 * 16 + mrow) * 32 + kq * 8]; \
      _Pragma("unroll")                                                        \
      for (int mt = 0; mt < 2; ++mt)                                           \
        _Pragma("unroll")                                                      \
        for (int nt2 = 0; nt2 < 2; ++nt2)                                      \
          acc[mt][nt2] = __builtin_amdgcn_mfma_f32_16x16x32_bf16(af[mt], bf[nt2], acc[mt][nt2], 0, 0, 0); \
    }                                                                          \
  }

// ---- 64x64 bf16 NT GEMM, BK=64 --------------------------------------------
template <int EPI>
__launch_bounds__(256)
__global__ void gemm_bf16_nt64(const ushort_t* __restrict__ A, const ushort_t* __restrict__ B,
                               const float* __restrict__ bias, float* __restrict__ C32,
                               ushort_t* __restrict__ C16, int M, int N, int Kd) {
  __shared__ __align__(16) ushort_t As[2][4096];
  __shared__ __align__(16) ushort_t Bs[2][4096];
  int tid = threadIdx.x;
  XCD_SWZ(64)
  GEMM64_PRE(A, B, Kd)
  f32x4 acc[2][2];
  #pragma unroll
  for (int i = 0; i < 2; ++i)
    #pragma unroll
    for (int j = 0; j < 2; ++j)
      #pragma unroll
      for (int r = 0; r < 4; ++r) acc[i][j][r] = 0.f;
  GEMM64_LOOP(Kd)
  #pragma unroll
  for (int mt = 0; mt < 2; ++mt)
    #pragma unroll
    for (int nt2 = 0; nt2 < 2; ++nt2) {
      int n_g = bn + wn + nt2 * 16 + (lane & 15);
      #pragma unroll
      for (int r = 0; r < 4; ++r) {
        int m_g = bm + wm + mt * 16 + kq * 4 + r;
        float v = acc[mt][nt2][r];
        if (bias) v += bias[n_g];
        if (EPI == EPI_LEAKY) v = LEAKY(v);
        else if (EPI == EPI_LEAKY_BN) { v = LEAKY(v); v *= BN_SCALE; }
        else if (EPI == EPI_TANH) v = tanhf(v);
        if (C32) C32[(size_t)m_g * N + n_g] = v;
        if (C16) C16[(size_t)m_g * N + n_g] = f2bfu(v);
      }
    }
}

// ---- 64x64 NT GEMM, dual weight/bias selected by M-half, BK=64 ------------
template <int EPI>
__launch_bounds__(256)
__global__ void gemm_nt64_dual(const ushort_t* __restrict__ A, const ushort_t* __restrict__ B1,
                               const ushort_t* __restrict__ B2, const float* __restrict__ bias1,
                               const float* __restrict__ bias2, ushort_t* __restrict__ C16,
                               int M, int N, int Kd, int Msplit) {
  __shared__ __align__(16) ushort_t As[2][4096];
  __shared__ __align__(16) ushort_t Bs[2][4096];
  int tid = threadIdx.x;
  XCD_SWZ(64)
  const ushort_t* B = (bm < Msplit) ? B1 : B2;
  const float* bias = (bm < Msplit) ? bias1 : bias2;
  GEMM64_PRE(A, B, Kd)
  f32x4 acc[2][2];
  #pragma unroll
  for (int i = 0; i < 2; ++i)
    #pragma unroll
    for (int j = 0; j < 2; ++j)
      #pragma unroll
      for (int r = 0; r < 4; ++r) acc[i][j][r] = 0.f;
  GEMM64_LOOP(Kd)
  #pragma unroll
  for (int mt = 0; mt < 2; ++mt)
    #pragma unroll
    for (int nt2 = 0; nt2 < 2; ++nt2) {
      int n_g = bn + wn + nt2 * 16 + (lane & 15);
      #pragma unroll
      for (int r = 0; r < 4; ++r) {
        int m_g = bm + wm + mt * 16 + kq * 4 + r;
        float v = acc[mt][nt2][r] + bias[n_g];
        if (EPI == EPI_LEAKY) v = LEAKY(v);
        else if (EPI == EPI_LEAKY_BN) { v = LEAKY(v); v *= BN_SCALE; }
        C16[(size_t)m_g * N + n_g] = f2bfu(v);
      }
    }
}

// ---- 64x64 NT GEMM with column-split epilogue, BK=64 ----------------------
template <int EPI1, int EPI2>
__launch_bounds__(256)
__global__ void gemm_nt64_split(const ushort_t* __restrict__ A, const ushort_t* __restrict__ B,
                                const float* __restrict__ biasPk, float* __restrict__ C32,
                                ushort_t* __restrict__ C16, int M, int N, int Kd, int Nsplit) {
  __shared__ __align__(16) ushort_t As[2][4096];
  __shared__ __align__(16) ushort_t Bs[2][4096];
  int tid = threadIdx.x;
  XCD_SWZ(64)
  GEMM64_PRE(A, B, Kd)
  f32x4 acc[2][2];
  #pragma unroll
  for (int i = 0; i < 2; ++i)
    #pragma unroll
    for (int j = 0; j < 2; ++j)
      #pragma unroll
      for (int r = 0; r < 4; ++r) acc[i][j][r] = 0.f;
  GEMM64_LOOP(Kd)
  #pragma unroll
  for (int mt = 0; mt < 2; ++mt)
    #pragma unroll
    for (int nt2 = 0; nt2 < 2; ++nt2) {
      int n_g = bn + wn + nt2 * 16 + (lane & 15);
      #pragma unroll
      for (int r = 0; r < 4; ++r) {
        int m_g = bm + wm + mt * 16 + kq * 4 + r;
        float v = acc[mt][nt2][r] + biasPk[n_g];
        if (n_g < Nsplit) {
          if (EPI1 == EPI_LEAKY) v = LEAKY(v);
          else if (EPI1 == EPI_TANH) v = tanhf(v);
        } else {
          if (EPI2 == EPI_LEAKY) v = LEAKY(v);
          else if (EPI2 == EPI_TANH) v = tanhf(v);
        }
        if (C32) C32[(size_t)m_g * N + n_g] = v;
        if (C16) C16[(size_t)m_g * N + n_g] = f2bfu(v);
      }
    }
}

// ---- X3T producer for skip1/2 (roles swapped, bitwise-identical), BK=64 ---
__launch_bounds__(256)
__global__ void gemm_w3T_z(const ushort_t* __restrict__ W3a, const ushort_t* __restrict__ W3b,
                           const float* __restrict__ b3a, const float* __restrict__ b3b,
                           const ushort_t* __restrict__ dtb, ushort_t* __restrict__ X3T) {
  const int N = 2048, Kd = 256;
  int z = blockIdx.z;
  const ushort_t* A = z ? W3b : W3a;
  const float* bias = z ? b3b : b3a;
  const ushort_t* B = dtb + (size_t)z * 2048 * 256;
  ushort_t* C = X3T + (size_t)z * 256 * 2048;
  __shared__ __align__(16) ushort_t As[2][4096];
  __shared__ __align__(16) ushort_t Bs[2][4096];
  int tid = threadIdx.x;
  XCD_SWZ(64)
  GEMM64_PRE(A, B, Kd)
  f32x4 acc[2][2];
  #pragma unroll
  for (int i = 0; i < 2; ++i)
    #pragma unroll
    for (int j = 0; j < 2; ++j)
      #pragma unroll
      for (int r = 0; r < 4; ++r) acc[i][j][r] = 0.f;
  GEMM64_LOOP(Kd)
  #pragma unroll
  for (int mt = 0; mt < 2; ++mt)
    #pragma unroll
    for (int nt2 = 0; nt2 < 2; ++nt2) {
      int n_g = bn + wn + nt2 * 16 + (lane & 15);
      #pragma unroll
      for (int r = 0; r < 4; ++r) {
        int m_g = bm + wm + mt * 16 + kq * 4 + r;
        float v = acc[mt][nt2][r] + bias[m_g];
        v = LEAKY(v); v *= BN_SCALE;
        C[(size_t)m_g * N + n_g] = f2bfu(v);
      }
    }
}

// ---- XsKs_z = Smat_z @ X3T_z^T + dt_z, BK=64 ------------------------------
__launch_bounds__(256)
__global__ void gemm_ntt_res64_z(const ushort_t* __restrict__ SmatBase,
                                 const ushort_t* __restrict__ X3T,
                                 const ushort_t* __restrict__ dtb,
                                 ushort_t* __restrict__ XsKs) {
  const int N = 256, Kd = 2048;
  int z = blockIdx.z;
  const ushort_t* A = SmatBase + (size_t)z * 2048 * 2048;
  const ushort_t* B = X3T + (size_t)z * 256 * 2048;
  const ushort_t* R = dtb + (size_t)z * 2048 * 256;
  ushort_t* C = XsKs + (size_t)z * 2048 * 256;
  __shared__ __align__(16) ushort_t As[2][4096];
  __shared__ __align__(16) ushort_t Bs[2][4096];
  int tid = threadIdx.x;
  XCD_SWZ(64)
  GEMM64_PRE(A, B, Kd)
  f32x4 acc[2][2];
  #pragma unroll
  for (int i = 0; i < 2; ++i)
    #pragma unroll
    for (int j = 0; j < 2; ++j)
      #pragma unroll
      for (int r = 0; r < 4; ++r) acc[i][j][r] = 0.f;
  GEMM64_LOOP(Kd)
  #pragma unroll
  for (int mt = 0; mt < 2; ++mt)
    #pragma unroll
    for (int nt2 = 0; nt2 < 2; ++nt2) {
      int n_g = bn + wn + nt2 * 16 + (lane & 15);
      #pragma unroll
      for (int r = 0; r < 4; ++r) {
        int m_g = bm + wm + mt * 16 + kq * 4 + r;
        float v = acc[mt][nt2][r] + bfu2f(R[(size_t)m_g * N + n_g]);
        C[(size_t)m_g * N + n_g] = f2bfu(v);
      }
    }
}

// ---- attn2 fe GEMM: A = [Bfuse | broadcast M1b], Kd=512, N=256 ------------
__launch_bounds__(256)
__global__ void gemm_fe2(const ushort_t* __restrict__ Bf, const ushort_t* __restrict__ M1b,
                         const ushort_t* __restrict__ Bw, const float* __restrict__ bias,
                         ushort_t* __restrict__ C16) {
  const int N = 256, Kd = 512;
  __shared__ __align__(16) ushort_t As[2][4096];
  __shared__ __align__(16) ushort_t Bs[2][4096];
  int tid = threadIdx.x;
  XCD_SWZ(64)
  int wave = tid >> 6, lane = tid & 63;
  int wm = (wave >> 1) * 32, wn = (wave & 1) * 32;
  int mrow = lane & 15, kq = lane >> 4;
  int c0 = wave * 128 + lane;
  int c1 = c0 + 64;
  int r0_ = (c0 >> 2) & 63, off0 = (c0 >> 8) * 32 + (c0 & 3) * 8;
  int r1_ = (c1 >> 2) & 63, off1 = (c1 >> 8) * 32 + (c1 & 3) * 8;
  const ushort_t* gb0 = Bw + (size_t)(bn + r0_) * Kd + off0;
  const ushort_t* gb1 = Bw + (size_t)(bn + r1_) * Kd + off1;

  f32x4 acc[2][2];
  #pragma unroll
  for (int i = 0; i < 2; ++i)
    #pragma unroll
    for (int j = 0; j < 2; ++j)
      #pragma unroll
      for (int r = 0; r < 4; ++r) acc[i][j][r] = 0.f;

  gload16(Bf + (size_t)(bm + r0_) * 256 + off0, &As[0][c0 * 8]);
  gload16(Bf + (size_t)(bm + r1_) * 256 + off1, &As[0][c1 * 8]);
  gload16(gb0, &Bs[0][c0 * 8]);
  gload16(gb1, &Bs[0][c1 * 8]);
  for (int t = 0; t < 8; ++t) {
    int cur = t & 1;
    __syncthreads();
    if (t + 1 < 8) {
      int tn = t + 1;
      int ko = tn * 64;
      const ushort_t* a0 = (tn < 4) ? Bf + (size_t)(bm + r0_) * 256 + ko + off0
                                    : M1b + (ko - 256) + off0;
      const ushort_t* a1 = (tn < 4) ? Bf + (size_t)(bm + r1_) * 256 + ko + off1
                                    : M1b + (ko - 256) + off1;
      gload16(a0, &As[cur ^ 1][c0 * 8]);
      gload16(a1, &As[cur ^ 1][c1 * 8]);
      gload16(gb0 + ko, &Bs[cur ^ 1][c0 * 8]);
      gload16(gb1 + ko, &Bs[cur ^ 1][c1 * 8]);
    }
    #pragma unroll
    for (int ks = 0; ks < 2; ++ks) {
      bf16x8 af[2], bf[2];
      #pragma unroll
      for (int mt = 0; mt < 2; ++mt)
        af[mt] = *(const bf16x8*)&As[cur][ks * 2048 + (wm + mt * 16 + mrow) * 32 + kq * 8];
      #pragma unroll
      for (int nt2 = 0; nt2 < 2; ++nt2)
        bf[nt2] = *(const bf16x8*)&Bs[cur][ks * 2048 + (wn + nt2 * 16 + mrow) * 32 + kq * 8];
      #pragma unroll
      for (int mt = 0; mt < 2; ++mt)
        #pragma unroll
        for (int nt2 = 0; nt2 < 2; ++nt2)
          acc[mt][nt2] = __builtin_amdgcn_mfma_f32_16x16x32_bf16(af[mt], bf[nt2], acc[mt][nt2], 0, 0, 0);
    }
  }
  #pragma unroll
  for (int mt = 0; mt < 2; ++mt)
    #pragma unroll
    for (int nt2 = 0; nt2 < 2; ++nt2) {
      int n_g = bn + wn + nt2 * 16 + (lane & 15);
      #pragma unroll
      for (int r = 0; r < 4; ++r) {
        int m_g = bm + wm + mt * 16 + kq * 4 + r;
        float v = acc[mt][nt2][r] + bias[n_g];
        v = LEAKY(v);
        C16[(size_t)m_g * N + n_g] = f2bfu(v);
      }
    }
}

// ---- split-K TN GEMM: Mm = X12m[:, :128]^T @ X12m[:, 128:] ----------------
__global__ void gemm_tn_part(const ushort_t* __restrict__ X, float* __restrict__ part) {
  int tx = threadIdx.x & 15, ty = threadIdx.x >> 4;
  int i = blockIdx.y * 16 + ty, j = blockIdx.x * 16 + tx;
  int ks = blockIdx.z;
  float acc = 0.f;
  for (int k = ks * 128; k < ks * 128 + 128; ++k)
    acc += bfu2f(X[(size_t)k * 256 + i]) * bfu2f(X[(size_t)k * 256 + 128 + j]);
  part[(size_t)ks * 16384 + i * 128 + j] = acc;
}
__global__ void gemm_tn_reduce(const float* __restrict__ part, ushort_t* __restrict__ Mm) {
  int idx = blockIdx.x * 256 + threadIdx.x;
  float s = 0.f;
  #pragma unroll
  for (int ks = 0; ks < 16; ++ks) s += part[(size_t)ks * 16384 + idx];
  Mm[idx] = f2bfu(s);
}

// ---- 2-stage column softmax (partB folded into partC) ---------------------
__global__ void smax_partA(const ushort_t* __restrict__ Sb, float* __restrict__ pm,
                           float* __restrict__ pl, int N) {
  int z = blockIdx.z;
  const ushort_t* S = Sb + (size_t)z * 2048 * 2048;
  int t = threadIdx.x;
  int col = blockIdx.x * 64 + (t & 63);
  int g = t >> 6;
  int r0 = blockIdx.y * 128 + g;
  float vals[32];
  #pragma unroll
  for (int i = 0; i < 32; ++i)
    vals[i] = bfu2f(S[(size_t)(r0 + 4 * i) * N + col]);
  float m = -1e30f;
  #pragma unroll
  for (int i = 0; i < 32; ++i) m = fmaxf(m, vals[i]);
  float l = 0.f;
  #pragma unroll
  for (int i = 0; i < 32; ++i) l += expf(vals[i] - m);
  __shared__ float rm[4][64], rl[4][64];
  rm[g][t & 63] = m; rl[g][t & 63] = l;
  __syncthreads();
  if (g == 0) {
    int c = t & 63;
    float M0 = rm[0][c], L0 = rl[0][c];
    #pragma unroll
    for (int j = 1; j < 4; ++j) {
      float Mj = rm[j][c], Lj = rl[j][c];
      float nm = fmaxf(M0, Mj);
      L0 = L0 * expf(M0 - nm) + Lj * expf(Mj - nm);
      M0 = nm;
    }
    pm[((size_t)z * 16 + blockIdx.y) * N + col] = M0;
    pl[((size_t)z * 16 + blockIdx.y) * N + col] = L0;
  }
}
__global__ void smax_partC(ushort_t* __restrict__ Sb, const float* __restrict__ pm,
                           const float* __restrict__ pl, int N) {
  int z = blockIdx.z;
  ushort_t* S = Sb + (size_t)z * 2048 * 2048;
  int t = threadIdx.x;
  int col = blockIdx.x * 64 + (t & 63);
  int g = t >> 6;
  __shared__ float sgm[64], sgi[64];
  if (t < 64) {
    float m = -1e30f, l = 0.f;
    for (int b = 0; b < 16; ++b) {
      float bm = pm[((size_t)z * 16 + b) * N + col];
      float bl = pl[((size_t)z * 16 + b) * N + col];
      float nm = fmaxf(m, bm);
      l = l * expf(m - nm) + bl * expf(bm - nm);
      m = nm;
    }
    sgm[t] = m;
    sgi[t] = 1.f / l;
  }
  __syncthreads();
  float m = sgm[t & 63], inv = sgi[t & 63];
  int r0 = blockIdx.y * 128 + g;
  #pragma unroll 8
  for (int i = 0; i < 32; ++i) {
    size_t idx = (size_t)(r0 + 4 * i) * N + col;
    S[idx] = f2bfu(expf(bfu2f(S[idx]) - m) * inv);
  }
}

// ---- row squared-norms from bf16 (2 rows/block, vectorized) ---------------
__global__ void row_norm_bf16(const ushort_t* __restrict__ X, float* __restrict__ out, int Kd) {
  int r = blockIdx.x * 2 + (threadIdx.x >> 5);
  int l = threadIdx.x & 31;
  bf16x8 v = *(const bf16x8*)&X[(size_t)r * Kd + l * 8];
  float s = 0.f;
  #pragma unroll
  for (int j = 0; j < 8; ++j) { float f = bfu2f((ushort_t)v[j]); s += f * f; }
  for (int off = 16; off; off >>= 1) s += __shfl_down(s, off, 32);
  if (l == 0) out[r] = s;
}

// ---- mask scores: 32 blocks x (64 cols x 4 h-segments), LDS reduce --------
__global__ void mask_score(const float* __restrict__ A3, const float* __restrict__ w4,
                           const float* __restrict__ b4, float* __restrict__ s) {
  __shared__ float red[4][64];
  int t = threadIdx.x;
  int col = blockIdx.x * 64 + (t & 63);
  int seg = t >> 6;
  float acc = 0.f;
  for (int h = seg * 32; h < seg * 32 + 32; ++h)
    acc += A3[(size_t)h * 2048 + col] * w4[h];
  red[seg][t & 63] = acc;
  __syncthreads();
  if (seg == 0)
    s[col] = red[0][t] + red[1][t] + red[2][t] + red[3][t] + b4[0];
}

// ---- stable descending-argsort rank via LDS-staged scores -----------------
__global__ void topk_rank(const float* __restrict__ s, int* __restrict__ idx, int K, int S) {
  __shared__ float sv[2048];
  int t = threadIdx.x;
  for (int i = t; i < K; i += 256) sv[i] = s[i];
  __syncthreads();
  int j = blockIdx.x * 256 + t;
  if (j >= K) return;
  float sj = sv[j];
  int rank = 0;
  #pragma unroll 8
  for (int i = 0; i < 2048; ++i) {
    float si = sv[i];
    rank += (si > sj) || (si == sj && i < j);
  }
  if (rank < S) idx[rank] = j;
}

// ---- build cat = [B_dt | softmax(aff_s[:,idx],axis=1) | 0pad], bf16 -------
__global__ void build_cat(const ushort_t* __restrict__ Bdt, const ushort_t* __restrict__ affs,
                          const int* __restrict__ idx, ushort_t* __restrict__ cat) {
  int r = blockIdx.x, t = threadIdx.x;
  __shared__ float vals[256];
  __shared__ float red[256];
  float v = -1e30f;
  if (t < 204) {
    int ix = idx[t];
    ix = ix < 0 ? 0 : (ix > 2047 ? 2047 : ix);
    v = bfu2f(affs[(size_t)r * 2048 + ix]);
  }
  vals[t] = v;
  red[t] = v;
  __syncthreads();
  for (int off = 128; off; off >>= 1) { if (t < off) red[t] = fmaxf(red[t], red[t + off]); __syncthreads(); }
  float m = red[0];
  __syncthreads();
  float e = (t < 204) ? expf(vals[t] - m) : 0.f;
  red[t] = e;
  __syncthreads();
  for (int off = 128; off; off >>= 1) { if (t < off) red[t] += red[t + off]; __syncthreads(); }
  float inv = 1.f / red[0];
  cat[(size_t)r * 512 + t] = Bdt[(size_t)r * 256 + t];
  cat[(size_t)r * 512 + 256 + t] = (t < 204) ? f2bfu(e * inv) : (ushort_t)0;
}

// ---- a = leaky((AV*AU) @ aww.T + awb), AVU combined [2048,256] ------------
__global__ void attn_gate(const float* __restrict__ AVU, const float* __restrict__ aww,
                          const float* __restrict__ awb, float* __restrict__ a, int n) {
  int wave = threadIdx.x >> 6, lane = threadIdx.x & 63;
  int r = blockIdx.x * 4 + wave;
  if (r >= n) return;
  float s = 0.f;
  #pragma unroll
  for (int j = 0; j < 2; ++j) {
    int d = lane + 64 * j;
    s += AVU[(size_t)r * 256 + d] * AVU[(size_t)r * 256 + 128 + d] * aww[d];
  }
  for (int off = 32; off; off >>= 1) s += __shfl_down(s, off);
  if (lane == 0) {
    float acc = s + awb[0];
    a[r] = LEAKY(acc);
  }
}

// ---- softmax write-out only (A output for attention 2) --------------------
__global__ void softmax_out(const float* __restrict__ x, float* __restrict__ y2, int n) {
  __shared__ float red[256];
  int t = threadIdx.x;
  float m = -1e30f;
  for (int i = t; i < n; i += 256) m = fmaxf(m, x[i]);
  red[t] = m;
  __syncthreads();
  for (int off = 128; off; off >>= 1) { if (t < off) red[t] = fmaxf(red[t], red[t + off]); __syncthreads(); }
  m = red[0];
  __syncthreads();
  float s = 0.f;
  for (int i = t; i < n; i += 256) s += expf(x[i] - m);
  red[t] = s;
  __syncthreads();
  for (int off = 128; off; off >>= 1) { if (t < off) red[t] += red[t + off]; __syncthreads(); }
  float inv = 1.f / red[0];
  for (int i = t; i < n; i += 256)
    y2[i] = expf(x[i] - m) * inv;
}

// ---- fused softmax + weighted column sum (64 partials) --------------------
__global__ void colsum_sm(const float* __restrict__ avec, const ushort_t* __restrict__ H,
                          float* __restrict__ part, int n) {
  __shared__ float red[256];
  int t = threadIdx.x;
  float m = -1e30f;
  for (int i = t; i < n; i += 256) m = fmaxf(m, avec[i]);
  red[t] = m;
  __syncthreads();
  for (int off = 128; off; off >>= 1) { if (t < off) red[t] = fmaxf(red[t], red[t + off]); __syncthreads(); }
  m = red[0];
  __syncthreads();
  float s = 0.f;
  for (int i = t; i < n; i += 256) s += expf(avec[i] - m);
  red[t] = s;
  __syncthreads();
  for (int off = 128; off; off >>= 1) { if (t < off) red[t] += red[t + off]; __syncthreads(); }
  float inv = 1.f / red[0];
  int bk = blockIdx.x, c = t;
  float acc = 0.f;
  for (int r = bk; r < n; r += 64)
    acc += expf(avec[r] - m) * inv * bfu2f(H[(size_t)r * 256 + c]);
  part[bk * 256 + c] = acc;
}
__global__ void colsum_fin(const float* __restrict__ part, float* __restrict__ out) {
  int c = threadIdx.x;
  float s = 0.f;
  #pragma unroll
  for (int k = 0; k < 64; ++k) s += part[k * 256 + c];
  out[c] = s;
}

// ---- gemv, one wave per output row, coalesced W reads; dual f32/bf16 out --
__global__ void gemv_act(const float* __restrict__ x, const float* __restrict__ W,
                         const float* __restrict__ b, float* __restrict__ out,
                         ushort_t* __restrict__ out16, int O, int Kd, int act) {
  int wave = threadIdx.x >> 6, lane = threadIdx.x & 63;
  int o = blockIdx.x * 4 + wave;
  if (o >= O) return;
  float s = 0.f;
  for (int c = lane; c < Kd; c += 64) s += x[c] * W[(size_t)o * Kd + c];
  for (int off = 32; off; off >>= 1) s += __shfl_down(s, off);
  if (lane == 0) {
    float acc = s + (b ? b[o] : 0.f);
    float v = act ? LEAKY(acc) : acc;
    out[o] = v;
    if (out16) out16[o] = f2bfu(v);
  }
}

// ---- final sigmoid head: prod 4-way add + shfl tree (same order as before) -
__global__ void final_sig(const float* __restrict__ a2, const float* __restrict__ clsw,
                          const float* __restrict__ clsb, float* __restrict__ Yout) {
  __shared__ float prod[256];
  int t = threadIdx.x;
  if (t < 256) prod[t] = a2[t] * clsw[t];
  __syncthreads();
  if (t < 64) {
    float s = prod[t] + prod[t + 64] + prod[t + 128] + prod[t + 192];
    for (int off = 32; off; off >>= 1) s += __shfl_down(s, off);
    if (t == 0) {
      float y = s + clsb[0];
      y = 1.f / (1.f + expf(-y));
      y = fminf(fmaxf(y, 1e-5f), 1.f - 1e-5f);
      Yout[0] = y;
    }
  }
}

extern "C" void kernel_launch(void* const* d_in, const int* in_sizes, int n_in,
                              void* d_out, int out_size, void* d_ws, size_t ws_size,
                              hipStream_t stream) {
  auto IN = [&](int i) { return (const float*)d_in[i]; };
  (void)n_in; (void)in_sizes; (void)out_size;

  const int S = 204;
  float* out_f = (float*)d_out;

  float* W = (float*)d_ws;
  size_t off = 0;
  auto F = [&](size_t n) { float* p = W + off; off += n; return p; };
  auto FU = [&](size_t nus) { return (ushort_t*)F((nus + 1) / 2); };

  ushort_t* dt_b  = FU((size_t)4096 * 256);   // B_dt | KB_dt
  ushort_t* XsKs  = FU((size_t)4096 * 256);   // Xs | Ks
  ushort_t* X12b  = FU((size_t)4096 * 256);   // skip12 X1|X2 (also skip3 X12, mask X12m)
  ushort_t* X3sb  = FU((size_t)4096 * 256);   // skip12 X3T both z: [2][256][2048]
  ushort_t* aff_b = FU((size_t)2048 * 2048);
  float* AVU   = F((size_t)2048 * 256);
  ushort_t* Mm_b = FU((size_t)128 * 128);
  ushort_t* M1b  = FU(256);
  float* svec  = F(2048);
  int*   idxb  = (int*)F(256);
  float* avec  = F(2048);
  float* AH    = F(256);
  float* M1v   = F(256);
  float* AH2   = F(256);
  float* bvec_ws = F(512);
  float* a2_ws   = F(256);
  float* nxy   = F(4096);
  float* part  = F(16384);
  float* sm_pm = F((size_t)2 * 16 * 2048);
  float* sm_pl = F((size_t)2 * 16 * 2048);
  float* pbias = F(6 * 256);                  // packed: sk1, sk2, sk3, mask, a1vu, a2vu

  // bf16 weight arena
  size_t wo = 0;
  ushort_t* warena = (ushort_t*)F(3250000);
  auto WA = [&](size_t n) { ushort_t* p = warena + wo; wo = (wo + n + 15) & ~(size_t)15; return p; };
  ushort_t* w2p   = WA(40960);                 // conv2 relayout [64][640]
  ushort_t* embp  = WA(212992);                // embed weight padded [256][832]
  ushort_t* s1w1 = WA(32768); ushort_t* s1w2 = WA(32768); ushort_t* s1w3 = WA(65536);
  ushort_t* s2w1 = WA(32768); ushort_t* s2w2 = WA(32768); ushort_t* s2w3 = WA(65536);
  ushort_t* s3w1 = WA(262144); ushort_t* s3w2 = WA(262144); ushort_t* s3w3 = WA(4194304);
  ushort_t* mw1 = WA(262144); ushort_t* mw2 = WA(262144); ushort_t* mw3 = WA(262144);
  ushort_t* fwp = WA(131072);
  ushort_t* a1fe = WA(65536); ushort_t* a1v = WA(32768); ushort_t* a1u = WA(32768);
  ushort_t* a2fe = WA(131072); ushort_t* a2v = WA(32768); ushort_t* a2u = WA(32768);
  (void)s1w2; (void)s2w2; (void)s3w2; (void)mw2; (void)a1u; (void)a2u;

  float* pool = F((size_t)4194304);           // 16 MB phase-shared

  const size_t NEED_BYTES = off * 4;
  if (ws_size < NEED_BYTES) {
    fill_out<<<9, 256, 0, stream>>>(out_f, 2049);
    return;
  }

  // pool phases
  ushort_t* h2h_b   = (ushort_t*)pool;               // conv: 4096*832 us
  ushort_t* SmatB   = (ushort_t*)pool;               // skip12: 2 x 2048^2 us (16MB)
  ushort_t* X3b_b   = (ushort_t*)(pool + 2097152);   // skip3: X3T 2048*2048 us
  float* A3   = pool;                                // mask: 128*2048 f
  float* tnpt = pool + 262144;                       // mask: 16*16384 f
  ushort_t* cat_b   = (ushort_t*)pool;               // fuse: 2048*512 us
  ushort_t* Bfuse_b = (ushort_t*)(pool + 1048576);
  ushort_t* Hbuf_b  = (ushort_t*)(pool + 1310720);

  // ---- weight conversion + packing ----
  CvtArgs ca;
  const float* srcs[20] = { IN(6), IN(8), IN(10), IN(12), IN(14), IN(16), IN(18),
                            IN(20), IN(22), IN(24), IN(26), IN(28), IN(30),
                            IN(36), IN(38), IN(40), IN(46), IN(48), IN(50), IN(4) };
  ushort_t* dsts[20] = { nullptr, s1w1, s1w2, s1w3, s2w1, s2w2, s2w3,
                         s3w1, s3w2, s3w3, mw1, mw2, mw3,
                         a1fe, a1v, a1u, a2fe, a2v, a2u, w2p };
  int lens[20] = { 0, 32768, 32768, 65536, 32768, 32768, 65536,
                   262144, 262144, 4194304, 262144, 262144, 262144,
                   65536, 32768, 32768, 131072, 32768, 32768, 0 };
  int cum = 0;
  for (int i = 0; i < 20; ++i) {
    ca.src[i] = srcs[i]; ca.dst[i] = dsts[i] ? dsts[i] : w2p;
    ca.cum[i] = cum; cum += lens[i];
  }
  ca.cum[20] = cum;
  to_bf16_flat<<<2048, 256, 0, stream>>>(ca);
  w2_relayout<<<160, 256, 0, stream>>>(IN(4), w2p);
  pad_rows_bf16<<<512, 256, 0, stream>>>(IN(34), fwp, 256, 460, 512);
  pad_rows_bf16<<<832, 256, 0, stream>>>(IN(6), embp, 256, 800, 832);
  BiasPk bp;
  const float* bsrc[12] = { IN(9), IN(11), IN(15), IN(17), IN(21), IN(23),
                            IN(27), IN(29), IN(39), IN(41), IN(49), IN(51) };
  for (int i = 0; i < 12; ++i) bp.a[i] = bsrc[i];
  bp.out = pbias;
  bias_pack<<<6, 256, 0, stream>>>(bp);
  float* pb_sk1 = pbias, *pb_sk2 = pbias + 256, *pb_sk3 = pbias + 512;
  float* pb_msk = pbias + 768, *pb_a1 = pbias + 1024, *pb_a2 = pbias + 1280;

  // ---- conv + embedding for B and KB in single dispatches ----
  conv12_mfma<<<2048, 256, 0, stream>>>(IN(0), IN(1), IN(2), IN(3), w2p, IN(5), h2h_b);
  gemm_bf16_nt64<EPI_LEAKY><<<dim3(4, 64), 256, 0, stream>>>(
      h2h_b, embp, IN(7), nullptr, dt_b, 4096, 256, 832);

  // ---- skip1+skip2, both branches fused (X3 produced transposed) ----
  gemm_nt64_dual<EPI_LEAKY_BN><<<dim3(4, 64), 256, 0, stream>>>(
      dt_b, s1w1, s2w1, pb_sk1, pb_sk2, X12b, 4096, 256, 256, 2048);
  gemm_w3T_z<<<dim3(32, 4, 2), 256, 0, stream>>>(s1w3, s2w3, IN(13), IN(19), dt_b, X3sb);
  gemm_smat_z<<<dim3(16, 16, 2), 256, 0, stream>>>(X12b, SmatB);
  smax_partA<<<dim3(32, 16, 2), 256, 0, stream>>>(SmatB, sm_pm, sm_pl, 2048);
  smax_partC<<<dim3(32, 16, 2), 256, 0, stream>>>(SmatB, sm_pm, sm_pl, 2048);
  gemm_ntt_res64_z<<<dim3(4, 32, 2), 256, 0, stream>>>(SmatB, X3sb, dt_b, XsKs);

  // ---- euclid -> aff_b ----
  row_norm_bf16<<<2048, 64, 0, stream>>>(XsKs, nxy, 256);
  gemm_bf16_nt<EPI_EUCLID><<<dim3(16, 16), 256, 0, stream>>>(
      XsKs, XsKs + (size_t)2048 * 256, nullptr, nullptr, aff_b, 2048, 2048, 256,
      nxy, nxy + 2048);

  // ---- skip3 (aff in-place; X3 produced transposed -> both big GEMMs NT) ----
  gemm_bf16_nt64<EPI_LEAKY_BN><<<dim3(4, 32), 256, 0, stream>>>(
      aff_b, s3w1, pb_sk3, nullptr, X12b, 2048, 256, 2048);
  gemm_smat_z<<<dim3(16, 16, 1), 256, 0, stream>>>(X12b, SmatB);
  gemm_bf16_nt<EPI_LEAKY_BN_ROW><<<dim3(16, 16), 256, 0, stream>>>(
      s3w3, aff_b, IN(25), nullptr, X3b_b, 2048, 2048, 2048, nullptr, nullptr);
  smax_partA<<<dim3(32, 16, 1), 256, 0, stream>>>(SmatB, sm_pm, sm_pl, 2048);
  smax_partC<<<dim3(32, 16, 1), 256, 0, stream>>>(SmatB, sm_pm, sm_pl, 2048);
  gemm_bf16_nt<EPI_RES><<<dim3(16, 16), 256, 0, stream>>>(
      SmatB, X3b_b, nullptr, nullptr, aff_b, 2048, 2048, 2048,
      (const float*)aff_b, nullptr);
  ushort_t* affs_b = aff_b;

  // ---- mask_scores -> top-S idx ----
  gemm_nt64_split<EPI_LEAKY, EPI_TANH><<<dim3(4, 32), 256, 0, stream>>>(
      affs_b, mw1, pb_msk, nullptr, X12b, 2048, 256, 2048, 128);
  gemm_tn_part<<<dim3(8, 8, 16), 256, 0, stream>>>(X12b, tnpt);
  gemm_tn_reduce<<<64, 256, 0, stream>>>(tnpt, Mm_b);
  gemm_bf16_nt64<EPI_LEAKY><<<dim3(32, 2), 256, 0, stream>>>(
      Mm_b, mw3, IN(31), A3, nullptr, 128, 2048, 128);
  mask_score<<<32, 256, 0, stream>>>(A3, IN(32), IN(33), svec);
  topk_rank<<<8, 256, 0, stream>>>(svec, idxb, 2048, S);

  // ---- B_bag + concat + fuse ----
  build_cat<<<2048, 256, 0, stream>>>(dt_b, affs_b, idxb, cat_b);
  gemm_bf16_nt64<EPI_LEAKY><<<dim3(4, 32), 256, 0, stream>>>(
      cat_b, fwp, IN(35), nullptr, Bfuse_b, 2048, 256, 512);

  // ---- attention 1 ----
  gemm_bf16_nt64<EPI_LEAKY><<<dim3(4, 32), 256, 0, stream>>>(
      Bfuse_b, a1fe, IN(37), nullptr, Hbuf_b, 2048, 256, 256);
  gemm_nt64_split<EPI_TANH, EPI_LEAKY><<<dim3(4, 32), 256, 0, stream>>>(
      Hbuf_b, a1v, pb_a1, AVU, nullptr, 2048, 256, 256, 128);
  attn_gate<<<512, 256, 0, stream>>>(AVU, IN(42), IN(43), avec, 2048);
  colsum_sm<<<64, 256, 0, stream>>>(avec, Hbuf_b, part, 2048);
  colsum_fin<<<1, 256, 0, stream>>>(part, AH);
  gemv_act<<<64, 256, 0, stream>>>(AH, IN(44), IN(45), M1v, M1b, 256, 256, 1);

  // ---- attention 2 (A -> output); A-operand streamed from [Bfuse | M1b] ----
  gemm_fe2<<<dim3(4, 32), 256, 0, stream>>>(Bfuse_b, M1b, a2fe, IN(47), Hbuf_b);
  gemm_nt64_split<EPI_TANH, EPI_LEAKY><<<dim3(4, 32), 256, 0, stream>>>(
      Hbuf_b, a2v, pb_a2, AVU, nullptr, 2048, 256, 256, 128);
  attn_gate<<<512, 256, 0, stream>>>(AVU, IN(52), IN(53), avec, 2048);
  softmax_out<<<1, 256, 0, stream>>>(avec, out_f + 1, 2048);
  colsum_sm<<<64, 256, 0, stream>>>(avec, Hbuf_b, part, 2048);
  colsum_fin<<<1, 256, 0, stream>>>(part, AH2);

  // ---- final head: parallel gemvs + tiny sigmoid (same summation order) ----
  gemv_act<<<128, 256, 0, stream>>>(AH2, IN(54), IN(55), bvec_ws, nullptr, 512, 256, 1);
  gemv_act<<<64, 256, 0, stream>>>(bvec_ws, IN(56), IN(57), a2_ws, nullptr, 256, 512, 1);
  final_sig<<<1, 256, 0, stream>>>(a2_ws, IN(58), IN(59), out_f);
}